// Round 6
// baseline (388.923 us; speedup 1.0000x reference)
//
#include <hip/hip_runtime.h>
#include <cstdint>
#include <cmath>

typedef __bf16 bf16;
typedef __attribute__((ext_vector_type(8))) __bf16 bf16x8;
typedef __attribute__((ext_vector_type(4))) __bf16 bf16x4;
typedef __attribute__((ext_vector_type(2))) __bf16 bf16x2;
typedef __attribute__((ext_vector_type(4))) float f32x4;
typedef __attribute__((ext_vector_type(16))) float f32x16;

constexpr int B_ = 2, T_ = 2048, C_ = 1024, H_ = 16, HD_ = 64;
constexpr int M_ = B_ * T_;   // 4096

#define EXP2F(x) __builtin_amdgcn_exp2f(x)
#define LOG2F(x) __builtin_amdgcn_logf(x)
#define SQRTF(x) __builtin_amdgcn_sqrtf(x)
#define RCPF(x)  __builtin_amdgcn_rcpf(x)

// ---- async global->LDS, 16B per lane; LDS dest = wave-uniform base + lane*16 ----
__device__ __forceinline__ void gld16(const void* g, void* l) {
  __builtin_amdgcn_global_load_lds((const __attribute__((address_space(1))) void*)g,
                                   (__attribute__((address_space(3))) void*)l, 16, 0, 0);
}

// ============  fused weight cast fp32 -> bf16 (w_uv/b_uv row-PERMUTED)  ============
// Permutation (for the 256^2 swiglu GEMM): 64-row groups of {32 u, 32 v}:
//   perm row 64g+i = u[32g+i]      (i < 32)
//                  = v[32g+i-32]   (i >= 32)
__global__ __launch_bounds__(256) void cast_all_kernel(const float* __restrict__ s0,
                                                       const float* __restrict__ s1,
                                                       const float* __restrict__ s2,
                                                       const float* __restrict__ s3,
                                                       const float* __restrict__ s4,
                                                       bf16* __restrict__ d0,
                                                       bf16* __restrict__ d1,
                                                       bf16* __restrict__ d2,
                                                       bf16* __restrict__ d3,
                                                       float* __restrict__ d4) {
  size_t gid = (size_t)blockIdx.x * 256 + threadIdx.x;
  if (gid >= 786432 + 262144 + 2097152 + 1048576) {
    size_t g4 = gid - (786432 + 262144 + 2097152 + 1048576);
    if (g4 >= 2048) return;
    int r = (int)(g4 * 4);
    int dr;
    if (r < 4096) { int g = r >> 5, i = r & 31; dr = g * 64 + i; }
    else { int j = r - 4096; int g = j >> 5, i = j & 31; dr = g * 64 + 32 + i; }
    *(f32x4*)(d4 + dr) = *(const f32x4*)(s4 + r);
    return;
  }
  const float* src;
  bf16* dst;
  size_t dstoff;
  if (gid < 786432) { src = s0; dst = d0; dstoff = gid * 4; }
  else if (gid < 786432 + 262144) { gid -= 786432; src = s1; dst = d1; dstoff = gid * 4; }
  else if (gid < 786432 + 262144 + 2097152) {
    gid -= 786432 + 262144; src = s2; dst = d2;
    size_t elem = gid * 4;
    int r = (int)(elem >> 10), c = (int)(elem & 1023);
    int dr;
    if (r < 4096) { int g = r >> 5, i = r & 31; dr = g * 64 + i; }
    else { int j = r - 4096; int g = j >> 5, i = j & 31; dr = g * 64 + 32 + i; }
    dstoff = ((size_t)dr << 10) | (size_t)c;
  }
  else { gid -= 786432 + 262144 + 2097152; src = s3; dst = d3; dstoff = gid * 4; }
  f32x4 v = *(const f32x4*)(src + gid * 4);
  bf16x4 o;
  o[0] = (bf16)v[0]; o[1] = (bf16)v[1]; o[2] = (bf16)v[2]; o[3] = (bf16)v[3];
  *(bf16x4*)(dst + dstoff) = o;
}

// =============  128x128 free-running GEMM, 32x32x16 MFMA  =============
// Counted-vmcnt 2-barrier/tile schedule (verified R3-R5); this round: MFMA shape
// 16x16x32 -> 32x32x16 (shape ceiling 2075 -> 2495 TF, same LDS bytes, half the
// MFMA instructions).  4 waves (2x2), wave C = 64x64 = 2x2 of 32x32 (acc 2x2
// f32x16 = 64 AGPR).  C/D layout (HW-verified m74/m101): col=lane&31,
// row=(reg&3)+8*(reg>>2)+4*(lane>>5).  A/B frag: row/col=lane&31, k-half=lane>>5.
// MODE 0: C=AB  1: +R  2: +bias  3: +bias+R
template <int MODE, typename OutT>
__global__ __launch_bounds__(256, 2) void gemm_fr(const bf16* __restrict__ A,
                                                  const bf16* __restrict__ Bw,
                                                  OutT* __restrict__ Cmat,
                                                  const float* __restrict__ bias,
                                                  const float* __restrict__ R,
                                                  int N, int K) {
  __shared__ __align__(16) bf16 smem[2][2][128][64];   // [buf][A=0/B=1][row][k] 64 KB

  const int tid  = threadIdx.x;
  const int wave = tid >> 6, lane = tid & 63;
  const int l32 = lane & 31, lk = lane >> 5;
  const int wm = wave >> 1, wn = wave & 1;
  const int bm = blockIdx.x * 128;
  const int bn = blockIdx.y * 128;

  // staging: thread -> row (tid>>3), 16B chunk (tid&7); source chunk
  // inverse-swizzled (chunk ^ row&7) so linear gld16 dest + swizzled ds_read
  // compose to identity.
  const int csw = (tid & 7) ^ ((tid >> 3) & 7);
  const bf16* gA = A  + (size_t)(bm + (tid >> 3)) * K + csw * 8;
  const bf16* gB = Bw + (size_t)(bn + (tid >> 3)) * K + csw * 8;
  const int wrow = wave * 8;     // wave-uniform LDS dest row base per gld16
  const int r7 = lane & 7;       // read-side swizzle key (row&7 == lane&7)

  f32x16 acc[2][2];
#pragma unroll
  for (int i = 0; i < 2; i++)
#pragma unroll
    for (int j = 0; j < 2; j++)
#pragma unroll
      for (int e = 0; e < 16; e++) acc[i][j][e] = 0.f;

#define STG(buf_, tile_, mat_, g_) do {                                        \
    const bf16* s_ = (mat_ ? gB : gA) + (size_t)((g_) * 32) * K + (size_t)(tile_) * 64; \
    gld16(s_, &smem[buf_][mat_][(g_) * 32 + wrow][0]);                         \
  } while (0)
#define STG_ALL(buf_, tile_) do {                                              \
    STG(buf_, tile_, 0, 0); STG(buf_, tile_, 0, 1);                            \
    STG(buf_, tile_, 0, 2); STG(buf_, tile_, 0, 3);                            \
    STG(buf_, tile_, 1, 0); STG(buf_, tile_, 1, 1);                            \
    STG(buf_, tile_, 1, 2); STG(buf_, tile_, 1, 3); } while (0)

  const int NT = K >> 6;
  STG_ALL(0, 0);
  STG_ALL(1, 1);
  asm volatile("s_waitcnt vmcnt(8)" ::: "memory");
  asm volatile("s_barrier" ::: "memory");

#pragma unroll 1
  for (int t = 0; t < NT; ++t) {
    const int buf = t & 1;
    bf16x8 afr[2][4], bfr[2][4];   // [mt|nt2][ks]
#pragma unroll
    for (int n2 = 0; n2 < 2; n2++)
#pragma unroll
      for (int ks = 0; ks < 4; ks++)
        bfr[n2][ks] = *(const bf16x8*)
            &smem[buf][1][wn * 64 + n2 * 32 + l32][((((ks << 1) | lk)) ^ r7) * 8];
#pragma unroll
    for (int mt = 0; mt < 2; mt++)
#pragma unroll
      for (int ks = 0; ks < 4; ks++)
        afr[mt][ks] = *(const bf16x8*)
            &smem[buf][0][wm * 64 + mt * 32 + l32][((((ks << 1) | lk)) ^ r7) * 8];

    __builtin_amdgcn_s_setprio(1);
#pragma unroll
    for (int ks = 0; ks < 4; ks++)
#pragma unroll
      for (int mt = 0; mt < 2; mt++)
#pragma unroll
        for (int n2 = 0; n2 < 2; n2++)
          acc[mt][n2] = __builtin_amdgcn_mfma_f32_32x32x16_bf16(
              afr[mt][ks], bfr[n2][ks], acc[mt][n2], 0, 0, 0);
    __builtin_amdgcn_s_setprio(0);

    if (t + 1 < NT) {
      asm volatile("s_barrier" ::: "memory");            // all waves done reading buf
      if (t + 2 < NT) {
        STG_ALL(buf, t + 2);                             // 8 loads into freed buf
        asm volatile("s_waitcnt vmcnt(8)" ::: "memory"); // t+1 drained; t+2 in flight
      } else {
        asm volatile("s_waitcnt vmcnt(0)" ::: "memory");
      }
      asm volatile("s_barrier" ::: "memory");            // t+1's LDS visible to all
    }
  }
#undef STG_ALL
#undef STG

#pragma unroll
  for (int mt = 0; mt < 2; mt++)
#pragma unroll
    for (int n2 = 0; n2 < 2; n2++) {
      const int col = bn + wn * 64 + n2 * 32 + l32;
      float bval = 0.f;
      if (MODE & 2) bval = bias[col];
#pragma unroll
      for (int reg = 0; reg < 16; reg++) {
        const int row = bm + wm * 64 + mt * 32 + (reg & 3) + 8 * (reg >> 2) + 4 * lk;
        float v = acc[mt][n2][reg] + bval;
        if (MODE & 1) v += R[(size_t)row * N + col];
        Cmat[(size_t)row * N + col] = (OutT)v;
      }
    }
}

// =====================  256x256 GEMM + swiglu, 32x32x16 MFMA  =====================
// Same counted-vmcnt 2-barrier/tile schedule (R3); MFMA shape upgraded.  8 waves
// (2Mx4N), wave C = 128x64 = 4x2 of 32x32 (acc 4x2 f32x16 = 128 AGPR).  A-frags
// stream per-mt with named ping-pong buffers; bfr preloaded.  T2 swizzle unchanged
// (2-way free under quarter-wave b128 processing).  Swiglu: u=acc[mt][0], v=acc[mt][1].
__global__ __launch_bounds__(512, 2) void gemm8_swiglu(const bf16* __restrict__ A,
                                                       const bf16* __restrict__ Bw,
                                                       bf16* __restrict__ Cmat,
                                                       const float* __restrict__ bias) {
  constexpr int K = 1024, NTILE = K / 64;   // 16 K-tiles
  __shared__ __align__(16) bf16 smem[2][2][256][64];   // [buf][A=0/B=1][row][k]

  const int tid  = threadIdx.x;
  const int wave = tid >> 6, lane = tid & 63;
  const int l32 = lane & 31, lk = lane >> 5;
  const int wm = wave >> 2, wn = wave & 3;
  const int bm = blockIdx.x * 256;
  const int bn = blockIdx.y * 256;

  const int csw = (tid & 7) ^ ((tid >> 3) & 7);
  const bf16* gA = A  + (size_t)(bm + (tid >> 3)) * K + csw * 8;
  const bf16* gB = Bw + (size_t)(bn + (tid >> 3)) * K + csw * 8;
  const int wrow = wave * 8;     // wave-uniform LDS dest row base per gld16
  const int r7 = lane & 7;       // read-side swizzle key

  f32x16 acc[4][2];
#pragma unroll
  for (int i = 0; i < 4; i++)
#pragma unroll
    for (int j = 0; j < 2; j++)
#pragma unroll
      for (int e = 0; e < 16; e++) acc[i][j][e] = 0.f;

#define STAGE8(buf_, tile_, h_) do {                                          \
    const int mat_ = (h_) >> 1;                                               \
    const int r0_  = ((h_) & 1) * 128;                                        \
    const bf16* s_ = (mat_ ? gB : gA) + (size_t)r0_ * K + (size_t)(tile_) * 64; \
    bf16* d_ = &smem[buf_][mat_][r0_ + wrow][0];                              \
    gld16(s_, d_);                                                            \
    gld16(s_ + (size_t)64 * K, d_ + 64 * 64);                                 \
  } while (0)
#define STAGE_ALL(buf_, tile_) do {                                           \
    STAGE8(buf_, tile_, 0); STAGE8(buf_, tile_, 1);                           \
    STAGE8(buf_, tile_, 2); STAGE8(buf_, tile_, 3); } while (0)

#define RD_A(mt_, ks_) (*(const bf16x8*)                                      \
    &smem[buf][0][wm * 128 + (mt_) * 32 + l32][((((ks_) << 1) | lk) ^ r7) * 8])

#define MT_CLUSTER(afv_, mt_) do {                                            \
    __builtin_amdgcn_s_setprio(1);                                            \
    _Pragma("unroll")                                                         \
    for (int ks = 0; ks < 4; ks++) {                                          \
      acc[mt_][0] = __builtin_amdgcn_mfma_f32_32x32x16_bf16(                  \
          afv_[ks], bfr[0][ks], acc[mt_][0], 0, 0, 0);                        \
      acc[mt_][1] = __builtin_amdgcn_mfma_f32_32x32x16_bf16(                  \
          afv_[ks], bfr[1][ks], acc[mt_][1], 0, 0, 0);                        \
    }                                                                         \
    __builtin_amdgcn_s_setprio(0);                                            \
  } while (0)

  // ---- prologue: stage tile0 + tile1 fully (16 loads); wait tile0 only ----
  STAGE_ALL(0, 0);
  STAGE_ALL(1, 1);
  asm volatile("s_waitcnt vmcnt(8)" ::: "memory");
  asm volatile("s_barrier" ::: "memory");

#pragma unroll 1
  for (int t = 0; t < NTILE; ++t) {
    const int buf = t & 1;
    bf16x8 bfr[2][4];
#pragma unroll
    for (int n2 = 0; n2 < 2; n2++)
#pragma unroll
      for (int ks = 0; ks < 4; ks++)
        bfr[n2][ks] = *(const bf16x8*)
            &smem[buf][1][wn * 64 + n2 * 32 + l32][((((ks << 1) | lk)) ^ r7) * 8];

    bf16x8 afA[4], afB[4];
#pragma unroll
    for (int ks = 0; ks < 4; ks++) afA[ks] = RD_A(0, ks);
#pragma unroll
    for (int ks = 0; ks < 4; ks++) afB[ks] = RD_A(1, ks);
    MT_CLUSTER(afA, 0);
#pragma unroll
    for (int ks = 0; ks < 4; ks++) afA[ks] = RD_A(2, ks);
    MT_CLUSTER(afB, 1);
#pragma unroll
    for (int ks = 0; ks < 4; ks++) afB[ks] = RD_A(3, ks);
    MT_CLUSTER(afA, 2);
    MT_CLUSTER(afB, 3);

    // ---- tile boundary: 2 barriers, counted vmcnt (never 0 mid-loop) ----
    if (t + 1 < NTILE) {
      asm volatile("s_barrier" ::: "memory");           // all waves done reading buf
      if (t + 2 < NTILE) {
        STAGE_ALL(buf, t + 2);                          // 8 loads into freed buf
        asm volatile("s_waitcnt vmcnt(8)" ::: "memory");// t+1's 8 drained; t+2 in flight
      } else {
        asm volatile("s_waitcnt vmcnt(0)" ::: "memory");// last tile: full drain
      }
      asm volatile("s_barrier" ::: "memory");           // t+1's LDS visible to all
    }
  }
#undef MT_CLUSTER
#undef RD_A
#undef STAGE_ALL
#undef STAGE8

  // ---- register-only swiglu epilogue: u = acc[mt][0], v = acc[mt][1] ----
  const int cg = (bn >> 1) + wn * 32 + l32;
  const float bu = bias[bn + wn * 64 + l32];
  const float bv = bias[bn + wn * 64 + 32 + l32];
#pragma unroll
  for (int mt = 0; mt < 4; mt++) {
#pragma unroll
    for (int reg = 0; reg < 16; reg++) {
      const int row = bm + wm * 128 + mt * 32 + (reg & 3) + 8 * (reg >> 2) + 4 * lk;
      float u = acc[mt][0][reg] + bu;
      float v = acc[mt][1][reg] + bv;
      float sig = RCPF(1.f + EXP2F(-v * 1.44269504f));
      Cmat[(size_t)row * 4096 + cg] = (bf16)(u * v * sig);
    }
  }
}

// =====================  RMSNorm: fp32 in -> bf16 out (row = 1024)  =====================
__global__ __launch_bounds__(256) void rmsnorm_kernel(const float* __restrict__ X,
                                                      bf16* __restrict__ O) {
  const int row = blockIdx.x;
  const int tid = threadIdx.x;
  const int wave = tid >> 6;
  f32x4 v = *(const f32x4*)(X + (size_t)row * C_ + tid * 4);
  float s = v[0] * v[0] + v[1] * v[1] + v[2] * v[2] + v[3] * v[3];
#pragma unroll
  for (int off = 32; off >= 1; off >>= 1) s += __shfl_xor(s, off);
  __shared__ float wsum[4];
  __shared__ float scale_sh;
  if ((tid & 63) == 0) wsum[wave] = s;
  __syncthreads();
  if (tid == 0)
    scale_sh = rsqrtf((wsum[0] + wsum[1] + wsum[2] + wsum[3]) * (1.f / (float)C_) + 1e-6f);
  __syncthreads();
  const float sc = scale_sh;
  bf16x4 o;
  o[0] = (bf16)(v[0] * sc); o[1] = (bf16)(v[1] * sc);
  o[2] = (bf16)(v[2] * sc); o[3] = (bf16)(v[3] * sc);
  *(bf16x4*)(O + (size_t)row * C_ + tid * 4) = o;
}

// ==========  Rotary on q,k (bf16, in-place) + q0/k0 = sqrt(kc + |.|^2)  ==========
__global__ __launch_bounds__(256) void rotary_kernel(bf16* __restrict__ qkv,
                                                     const float* __restrict__ kcb,
                                                     float* __restrict__ q0b,
                                                     float* __restrict__ k0b) {
  const int wid  = blockIdx.x * 4 + (threadIdx.x >> 6);  // one wave per (b,t,h)
  const int lane = threadIdx.x & 63;
  const int b = wid >> 15;          // T_*H_ = 32768
  const int rem = wid & 32767;
  const int t = rem >> 4;
  const int h = rem & 15;
  const int i = lane & 31;
  const float invf = expf(-((float)i / 32.f) * 9.210340371976184f);  // 10000^(-i/32)
  const float ang = (float)t * invf;
  const float cx = cosf(ang), sx = sinf(ang);
  const float kc = kcb[h];
  bf16* qp = qkv + (size_t)(b * T_ + t) * 3072 + h * 64;

#pragma unroll
  for (int which = 0; which < 2; which++) {
    bf16* p = qp + which * 1024;   // q then k
    float x1 = (float)p[i];
    float x2 = (float)p[i + 32];
    float o = (lane < 32) ? (x1 * cx + x2 * sx) : (x2 * cx - x1 * sx);
    float ss = o * o;
#pragma unroll
    for (int off = 32; off >= 1; off >>= 1) ss += __shfl_xor(ss, off);
    p[lane] = (bf16)o;
    if (lane == 0) {
      float* dst = which == 0 ? q0b : k0b;
      dst[(size_t)(b * H_ + h) * T_ + t] = SQRTF(kc + ss);
    }
  }
}

// =====================  Hyperbolic flash attention (v9)  =====================
// v9: CU-pair-complementary ty remap.  Blocks i and i+256 co-locate on the same CU
// (grid 32x16, x-fastest dispatch, 256%8==0 XCD round-robin).  y<8 -> ty=15-y
// (heavy, dispatched first, LPT), y>=8 -> ty=y-8 -> every CU pair sums to 34 iters.
__global__ __launch_bounds__(512) void attn_kernel(const bf16* __restrict__ qkv,
                                                   const float* __restrict__ q0b,
                                                   const float* __restrict__ k0b,
                                                   const float* __restrict__ kcb,
                                                   bf16* __restrict__ outp) {
  __shared__ __align__(16) bf16 Kls[2][64][72];
  __shared__ __align__(16) bf16 Vt[2][64][68];
  __shared__ __align__(16) bf16 Pls[8][16 * 36];
  __shared__ float k0s[2][64];

  const int tid = threadIdx.x;
  const int wave = tid >> 6, lane = tid & 63;
  const int quad = lane >> 4, l16 = lane & 15;
  const int bh = blockIdx.x;
  const int b = bh >> 4, h = bh & 15;

  const float kc = kcb[h];
  const float inv_kc = 1.f / kc;
  const float sqkc = SQRTF(kc);
  const int role = tid >> 8;            // 0: K crew, 1: V crew
  const int st = tid & 255;
  const int sp = st & 31, dq = st >> 5; // s-pair 0..31, d-chunk 0..7
  bf16* Pl = Pls[wave];
  const float* q0base = q0b + (size_t)(b * H_ + h) * T_;
  const float* k0base = k0b + (size_t)(b * H_ + h) * T_;

  const int yb = (int)blockIdx.y;
  const int ty = (yb < 8) ? (15 - yb) : (yb - 8);  // CU pair (y, y+8): 34 iters const
  const int t0 = ty * 128;
  const int tb = t0 + wave * 16;
  const int nIter = 2 * ty + 2;

  // q A-frags: A[m=l16][k=quad*8+j]
  const bf16* qrow = qkv + (size_t)(b * T_ + tb + l16) * 3072 + h * 64;
  bf16x8 aq0 = *(const bf16x8*)(qrow + quad * 8);
  bf16x8 aq1 = *(const bf16x8*)(qrow + 32 + quad * 8);
  float q0r[4];
#pragma unroll
  for (int r = 0; r < 4; r++) q0r[r] = q0base[tb + quad * 4 + r];

  f32x4 o[4];
#pragma unroll
  for (int dt = 0; dt < 4; dt++) o[dt] = f32x4{0.f, 0.f, 0.f, 0.f};
  float lrow[4] = {0.f, 0.f, 0.f, 0.f};

  // ---- prologue: prefetch tile 0.  role 0 loads K rows (2sp, 2sp+1); role 1 V.
  const bf16* base = qkv + (size_t)b * T_ * 3072 + 1024 + role * 1024 + h * 64 + dq * 8;
  bf16x8 pf_a = *(const bf16x8*)(base + (size_t)(2 * sp) * 3072);
  bf16x8 pf_b = *(const bf16x8*)(base + (size_t)(2 * sp + 1) * 3072);
  float k0v = (tid < 64) ? k0base[tid] : 0.f;

  for (int it = 0; it < nIter; ++it) {
    const int s0 = it * 64;
    const int buf = it & 1;
    // ---- commit prefetched tile ----
    if (role == 0) {
      *(bf16x8*)&Kls[buf][2 * sp][dq * 8]     = pf_a;
      *(bf16x8*)&Kls[buf][2 * sp + 1][dq * 8] = pf_b;
    } else {
#pragma unroll
      for (int i2 = 0; i2 < 8; i2++) {
        bf16x2 pr;
        pr[0] = pf_a[i2];
        pr[1] = pf_b[i2];
        *(bf16x2*)&Vt[buf][dq * 8 + i2][2 * sp] = pr;
      }
    }
    if (tid < 64) k0s[buf][tid] = k0v;
    __syncthreads();

    // ---- prefetch NEXT tile (clamped; latency overlaps compute) ----
    const int s0n = (it + 1 < nIter) ? s0 + 64 : s0;
    pf_a = *(const bf16x8*)(base + (size_t)(s0n + 2 * sp) * 3072);
    pf_b = *(const bf16x8*)(base + (size_t)(s0n + 2 * sp + 1) * 3072);
    if (tid < 64) k0v = k0base[s0n + tid];

    if (s0 <= tb + 15) {   // causal: this wave has live columns in the tile
      // ---- S = q @ K^T (four 16-col n-tiles) ----
      f32x4 sc[4];
#pragma unroll
      for (int nt = 0; nt < 4; nt++) {
        sc[nt] = f32x4{0.f, 0.f, 0.f, 0.f};
        bf16x8 b0 = *(const bf16x8*)&Kls[buf][nt * 16 + l16][quad * 8];
        bf16x8 b1 = *(const bf16x8*)&Kls[buf][nt * 16 + l16][32 + quad * 8];
        sc[nt] = __builtin_amdgcn_mfma_f32_16x16x32_bf16(aq0, b0, sc[nt], 0, 0, 0);
        sc[nt] = __builtin_amdgcn_mfma_f32_16x16x32_bf16(aq1, b1, sc[nt], 0, 0, 0);
      }

      // ---- p = exp(-dis) in two 32-col chunks; P roundtrip per chunk ----
      bf16x8 ap[2];
#pragma unroll
      for (int ck = 0; ck < 2; ck++) {
#pragma unroll
        for (int ntl = 0; ntl < 2; ntl++) {
          const int nt = ck * 2 + ntl;
          const float k0c = k0s[buf][nt * 16 + l16];
          const int s = s0 + nt * 16 + l16;
#pragma unroll
          for (int r = 0; r < 4; r++) {
            const int t = tb + quad * 4 + r;
            float lor = sc[nt][r] - q0r[r] * k0c;
            float ratio = fmaxf(-lor * inv_kc, 1.f + 1e-6f);
            float wv = ratio + SQRTF(ratio * ratio - 1.f);
            float p = EXP2F(-sqkc * LOG2F(wv));
            p = (s <= t) ? p : 0.f;
            lrow[r] += p;
            Pl[(quad * 4 + r) * 36 + ntl * 16 + l16] = (bf16)p;
          }
        }
        ap[ck] = *(const bf16x8*)&Pl[l16 * 36 + quad * 8];
      }
#pragma unroll
      for (int dt = 0; dt < 4; dt++) {
        bf16x8 bv0 = *(const bf16x8*)&Vt[buf][dt * 16 + l16][quad * 8];
        bf16x8 bv1 = *(const bf16x8*)&Vt[buf][dt * 16 + l16][32 + quad * 8];
        o[dt] = __builtin_amdgcn_mfma_f32_16x16x32_bf16(ap[0], bv0, o[dt], 0, 0, 0);
        o[dt] = __builtin_amdgcn_mfma_f32_16x16x32_bf16(ap[1], bv1, o[dt], 0, 0, 0);
      }
    }
  }

  // ---- one deferred l-reduction over the 16 l16 lanes, then write O ----
#pragma unroll
  for (int r = 0; r < 4; r++) {
#pragma unroll
    for (int off = 1; off <= 8; off <<= 1) lrow[r] += __shfl_xor(lrow[r], off);
  }
#pragma unroll
  for (int r = 0; r < 4; r++) {
    const float invl = RCPF(lrow[r]);
    const int t = tb + quad * 4 + r;
#pragma unroll
    for (int dt = 0; dt < 4; dt++) {
      float val = o[dt][r] * invl;
      outp[(size_t)(b * T_ + t) * C_ + h * 64 + dt * 16 + l16] = (bf16)val;
    }
  }
}

// =====================  host-side launch  =====================
extern "C" void kernel_launch(void* const* d_in, const int* in_sizes, int n_in,
                              void* d_out, int out_size, void* d_ws, size_t ws_size,
                              hipStream_t stream) {
  const float* x      = (const float*)d_in[0];
  const float* w_qkv  = (const float*)d_in[1];
  const float* w_out  = (const float*)d_in[2];
  const float* kcb    = (const float*)d_in[3];
  const float* w_uv   = (const float*)d_in[4];
  const float* b_uv   = (const float*)d_in[5];
  const float* w_mlp  = (const float*)d_in[6];
  const float* b_mlp  = (const float*)d_in[7];
  float* out = (float*)d_out;

  const size_t MB = 1024ull * 1024ull;
  char* w = (char*)d_ws;
  bf16*  wqkv_b  = (bf16*)(w + 0);          //  6 MB   [0,6)
  bf16*  wout_b  = (bf16*)(w + 6 * MB);     //  2 MB   [6,8)
  bf16*  wuv_p   = (bf16*)(w + 8 * MB);     // 16 MB   [8,24)  row-permuted {32u,32v}/64
  bf16*  wmlp_b  = (bf16*)(w + 24 * MB);    //  8 MB   [24,32)
  bf16*  hbuf    = (bf16*)(w + 32 * MB);    //  8 MB   [32,40)
  bf16*  qkvbuf  = (bf16*)(w + 40 * MB);    // 24 MB   [40,64) dead after attn
  bf16*  attnbuf = (bf16*)(w + 64 * MB);    //  8 MB   [64,72) dead after wout GEMM
  bf16*  gbuf    = (bf16*)(w + 40 * MB);    // 32 MB   [40,72) over qkv+attn (step 7)
  float* x2buf   = (float*)(w + 72 * MB);   // 16 MB   [72,88) fp32
  float* q0b     = (float*)(w + 88 * MB);                 // 256 KB
  float* k0b     = (float*)(w + 88 * MB + 256 * 1024);    // 256 KB
  float* biasp   = (float*)(w + 88 * MB + 512 * 1024);    //  32 KB (permuted b_uv)
  // total: ~88.6 MB

  // 0) weight casts (+w_uv/b_uv row permutation), single launch
  const int total4 = 786432 + 262144 + 2097152 + 1048576 + 2048;
  cast_all_kernel<<<(total4 + 255) / 256, 256, 0, stream>>>(
      w_qkv, w_out, w_uv, w_mlp, b_uv, wqkv_b, wout_b, wuv_p, wmlp_b, biasp);

  // 1) h = rmsnorm(x)
  rmsnorm_kernel<<<M_, 256, 0, stream>>>(x, hbuf);
  // 2) qkv = h @ w_qkv^T   (128^2 free-run 32x32, 768 blocks)
  gemm_fr<0, bf16><<<dim3(M_ / 128, 3072 / 128), 256, 0, stream>>>(
      hbuf, wqkv_b, qkvbuf, nullptr, nullptr, 3072, 1024);
  // 3) rotary(q,k) in-place + q0/k0
  rotary_kernel<<<(B_ * T_ * H_) / 4, 256, 0, stream>>>(qkvbuf, kcb, q0b, k0b);
  // 4) hyperbolic flash attention (v9: balanced CU pairs)
  attn_kernel<<<dim3(B_ * H_, 16), 512, 0, stream>>>(qkvbuf, q0b, k0b, kcb, attnbuf);
  // 5) x2 = x + attn @ w_out^T   (128^2 free-run 32x32, 256 blocks)
  gemm_fr<1, float><<<dim3(M_ / 128, 1024 / 128), 256, 0, stream>>>(
      attnbuf, wout_b, x2buf, nullptr, x, 1024, 1024);
  // 6) h2 = rmsnorm(x2)
  rmsnorm_kernel<<<M_, 256, 0, stream>>>(x2buf, hbuf);
  // 7) g = swiglu(h2 @ w_uv_p^T + b_uv_p) -> 4096-col bf16  (256^2 32x32)
  gemm8_swiglu<<<dim3(M_ / 256, 8192 / 256), 512, 0, stream>>>(hbuf, wuv_p, gbuf, biasp);
  // 8) out = x2 + g @ w_mlp^T + b_mlp   (128^2 free-run 32x32, K=4096, 256 blocks)
  gemm_fr<3, float><<<dim3(M_ / 128, 1024 / 128), 256, 0, stream>>>(
      gbuf, wmlp_b, out, b_mlp, x2buf, 1024, 4096);
}

// Round 8
// 383.121 us; speedup vs baseline: 1.0151x; 1.0151x over previous
//
#include <hip/hip_runtime.h>
#include <cstdint>
#include <cmath>

typedef __bf16 bf16;
typedef __attribute__((ext_vector_type(8))) __bf16 bf16x8;
typedef __attribute__((ext_vector_type(4))) __bf16 bf16x4;
typedef __attribute__((ext_vector_type(2))) __bf16 bf16x2;
typedef __attribute__((ext_vector_type(4))) float f32x4;

constexpr int B_ = 2, T_ = 2048, C_ = 1024, H_ = 16, HD_ = 64;
constexpr int M_ = B_ * T_;   // 4096

#define EXP2F(x) __builtin_amdgcn_exp2f(x)
#define LOG2F(x) __builtin_amdgcn_logf(x)
#define SQRTF(x) __builtin_amdgcn_sqrtf(x)
#define RCPF(x)  __builtin_amdgcn_rcpf(x)

// ---- async global->LDS, 16B per lane; LDS dest = wave-uniform base + lane*16 ----
__device__ __forceinline__ void gld16(const void* g, void* l) {
  __builtin_amdgcn_global_load_lds((const __attribute__((address_space(1))) void*)g,
                                   (__attribute__((address_space(3))) void*)l, 16, 0, 0);
}

// ============  fused weight cast fp32 -> bf16 (w_uv/b_uv row-PERMUTED)  ============
// Permutation (for the 256^2 swiglu GEMM): 64-row groups of {32 u, 32 v}:
//   perm row 64g+i = u[32g+i]      (i < 32)
//                  = v[32g+i-32]   (i >= 32)
__global__ __launch_bounds__(256) void cast_all_kernel(const float* __restrict__ s0,
                                                       const float* __restrict__ s1,
                                                       const float* __restrict__ s2,
                                                       const float* __restrict__ s3,
                                                       const float* __restrict__ s4,
                                                       bf16* __restrict__ d0,
                                                       bf16* __restrict__ d1,
                                                       bf16* __restrict__ d2,
                                                       bf16* __restrict__ d3,
                                                       float* __restrict__ d4) {
  size_t gid = (size_t)blockIdx.x * 256 + threadIdx.x;
  if (gid >= 786432 + 262144 + 2097152 + 1048576) {
    size_t g4 = gid - (786432 + 262144 + 2097152 + 1048576);
    if (g4 >= 2048) return;
    int r = (int)(g4 * 4);
    int dr;
    if (r < 4096) { int g = r >> 5, i = r & 31; dr = g * 64 + i; }
    else { int j = r - 4096; int g = j >> 5, i = j & 31; dr = g * 64 + 32 + i; }
    *(f32x4*)(d4 + dr) = *(const f32x4*)(s4 + r);
    return;
  }
  const float* src;
  bf16* dst;
  size_t dstoff;
  if (gid < 786432) { src = s0; dst = d0; dstoff = gid * 4; }
  else if (gid < 786432 + 262144) { gid -= 786432; src = s1; dst = d1; dstoff = gid * 4; }
  else if (gid < 786432 + 262144 + 2097152) {
    gid -= 786432 + 262144; src = s2; dst = d2;
    size_t elem = gid * 4;
    int r = (int)(elem >> 10), c = (int)(elem & 1023);
    int dr;
    if (r < 4096) { int g = r >> 5, i = r & 31; dr = g * 64 + i; }
    else { int j = r - 4096; int g = j >> 5, i = j & 31; dr = g * 64 + 32 + i; }
    dstoff = ((size_t)dr << 10) | (size_t)c;
  }
  else { gid -= 786432 + 262144 + 2097152; src = s3; dst = d3; dstoff = gid * 4; }
  f32x4 v = *(const f32x4*)(src + gid * 4);
  bf16x4 o;
  o[0] = (bf16)v[0]; o[1] = (bf16)v[1]; o[2] = (bf16)v[2]; o[3] = (bf16)v[3];
  *(bf16x4*)(dst + dstoff) = o;
}

// =============  128xBN free-running GEMM: C = A @ Bw^T (+bias)(+residual)  =============
// Verified counted-vmcnt 2-barrier/tile schedule (R3-R5), 16x16x32 MFMA (the
// conflict-free fragment-read pattern -- R6's 32x32 reads re-introduced 4-way
// conflicts and regressed; reverted).  BN=128: 4 waves of 64x64 C, 64 KB LDS,
// 8 loads/tile, vmcnt(8).  BN=64: 4 waves of 64x32 C, 48 KB LDS, 6 loads/tile,
// vmcnt(6) -> N=1024 grids become 512 blocks = 2 resident blocks/CU (boundary
// stalls overlap across blocks).  MODE 0: C=AB  1: +R  2: +bias  3: +bias+R
template <int MODE, typename OutT, int BN = 128>
__global__ __launch_bounds__(256, 2) void gemm_fr(const bf16* __restrict__ A,
                                                  const bf16* __restrict__ Bw,
                                                  OutT* __restrict__ Cmat,
                                                  const float* __restrict__ bias,
                                                  const float* __restrict__ R,
                                                  int N, int K) {
  constexpr int NTN = BN / 32;            // n-tiles per wave (4 or 2)
  __shared__ __align__(16) bf16 smA[2][128][64];
  __shared__ __align__(16) bf16 smB[2][BN][64];

  const int tid  = threadIdx.x;
  const int wave = tid >> 6, lane = tid & 63;
  const int quad = lane >> 4, l16 = lane & 15;
  const int wm = wave >> 1, wn = wave & 1;
  const int bm = blockIdx.x * 128;
  const int bn = blockIdx.y * BN;

  // staging: thread -> row (tid>>3) of a 32-row group, 16B chunk (tid&7); source
  // chunk inverse-swizzled (chunk ^ row&7) so linear gld16 dest + swizzled ds_read
  // compose to identity.
  const int csw = (tid & 7) ^ ((tid >> 3) & 7);
  const bf16* gA = A  + (size_t)(bm + (tid >> 3)) * K + csw * 8;
  const bf16* gB = Bw + (size_t)(bn + (tid >> 3)) * K + csw * 8;
  const int wrow = wave * 8;     // wave-uniform LDS dest row base per gld16
  const int r7 = l16 & 7;        // read-side swizzle key

  f32x4 acc[4][NTN];
#pragma unroll
  for (int i = 0; i < 4; i++)
#pragma unroll
    for (int j = 0; j < NTN; j++) acc[i][j] = f32x4{0.f, 0.f, 0.f, 0.f};

#define STG_ALL(buf_, tile_) do {                                              \
    _Pragma("unroll")                                                          \
    for (int g = 0; g < 4; g++)                                                \
      gld16(gA + (size_t)(g * 32) * K + (size_t)(tile_) * 64,                  \
            &smA[buf_][g * 32 + wrow][0]);                                     \
    _Pragma("unroll")                                                          \
    for (int g = 0; g < BN / 32; g++)                                          \
      gld16(gB + (size_t)(g * 32) * K + (size_t)(tile_) * 64,                  \
            &smB[buf_][g * 32 + wrow][0]);                                     \
  } while (0)

  const int NT = K >> 6;
  // ---- prologue: stage tile0 + tile1; counted wait for tile0 only ----
  STG_ALL(0, 0);
  STG_ALL(1, 1);
  if (BN == 128) asm volatile("s_waitcnt vmcnt(8)" ::: "memory");
  else           asm volatile("s_waitcnt vmcnt(6)" ::: "memory");
  asm volatile("s_barrier" ::: "memory");

#pragma unroll 1
  for (int t = 0; t < NT; ++t) {
    const int buf = t & 1;
    bf16x8 af[2][4], bfr[2][NTN];
    // ks=0 operands
#pragma unroll
    for (int nt = 0; nt < NTN; nt++)
      bfr[0][nt] = *(const bf16x8*)&smB[buf][wn * (BN / 2) + nt * 16 + l16][(quad ^ r7) * 8];
#pragma unroll
    for (int i = 0; i < 4; i++)
      af[0][i] = *(const bf16x8*)&smA[buf][wm * 64 + i * 16 + l16][(quad ^ r7) * 8];
    // prefetch ks=1 operands
#pragma unroll
    for (int nt = 0; nt < NTN; nt++)
      bfr[1][nt] = *(const bf16x8*)&smB[buf][wn * (BN / 2) + nt * 16 + l16][((4 + quad) ^ r7) * 8];
#pragma unroll
    for (int i = 0; i < 4; i++)
      af[1][i] = *(const bf16x8*)&smA[buf][wm * 64 + i * 16 + l16][((4 + quad) ^ r7) * 8];

    __builtin_amdgcn_s_setprio(1);
#pragma unroll
    for (int i = 0; i < 4; i++)
#pragma unroll
      for (int nt = 0; nt < NTN; nt++)
        acc[i][nt] = __builtin_amdgcn_mfma_f32_16x16x32_bf16(af[0][i], bfr[0][nt], acc[i][nt], 0, 0, 0);
    __builtin_amdgcn_s_setprio(0);
    __builtin_amdgcn_s_setprio(1);
#pragma unroll
    for (int i = 0; i < 4; i++)
#pragma unroll
      for (int nt = 0; nt < NTN; nt++)
        acc[i][nt] = __builtin_amdgcn_mfma_f32_16x16x32_bf16(af[1][i], bfr[1][nt], acc[i][nt], 0, 0, 0);
    __builtin_amdgcn_s_setprio(0);

    // ---- tile boundary: 2 barriers, counted vmcnt (never 0 mid-loop) ----
    if (t + 1 < NT) {
      asm volatile("s_barrier" ::: "memory");            // all waves done reading buf
      if (t + 2 < NT) {
        STG_ALL(buf, t + 2);                             // loads into freed buf
        if (BN == 128) asm volatile("s_waitcnt vmcnt(8)" ::: "memory");
        else           asm volatile("s_waitcnt vmcnt(6)" ::: "memory");
      } else {
        asm volatile("s_waitcnt vmcnt(0)" ::: "memory");
      }
      asm volatile("s_barrier" ::: "memory");            // t+1's LDS visible to all
    }
  }
#undef STG_ALL

#pragma unroll
  for (int mt = 0; mt < 4; mt++) {
    const int row = bm + wm * 64 + mt * 16 + quad * 4;
#pragma unroll
    for (int nt = 0; nt < NTN; nt++) {
      const int col = bn + wn * (BN / 2) + nt * 16 + l16;
      float bval = 0.f;
      if (MODE & 2) bval = bias[col];
#pragma unroll
      for (int r = 0; r < 4; r++) {
        float v = acc[mt][nt][r] + bval;
        if (MODE & 1) v += R[(size_t)(row + r) * N + col];
        Cmat[(size_t)(row + r) * N + col] = (OutT)v;
      }
    }
  }
}

// =====================  256x256 GEMM + swiglu epilogue (R5 structure)  =====================
// Structure at its measured ceiling for K=1024 (~930 TF): full-tile LDS double
// buffer, 2 barriers/tile, counted vmcnt (never 0 mid-loop), reg-dbuf phase
// pipeline, T2 3-bit chunk swizzle (bank-conflict == 0), T5 setprio, 16x16x32.
__global__ __launch_bounds__(512, 2) void gemm8_swiglu(const bf16* __restrict__ A,
                                                       const bf16* __restrict__ Bw,
                                                       bf16* __restrict__ Cmat,
                                                       const float* __restrict__ bias) {
  constexpr int K = 1024, NTILE = K / 64;   // 16 K-tiles
  __shared__ __align__(16) bf16 smem[2][2][256][64];   // [buf][A=0/B=1][row][k]

  const int tid  = threadIdx.x;
  const int wave = tid >> 6, lane = tid & 63;
  const int quad = lane >> 4, l16 = lane & 15;
  const int wm = wave >> 2, wn = wave & 3;
  const int bm = blockIdx.x * 256;
  const int bn = blockIdx.y * 256;

  const int csw = (tid & 7) ^ ((tid >> 3) & 7);
  const bf16* gA = A  + (size_t)(bm + (tid >> 3)) * K + csw * 8;
  const bf16* gB = Bw + (size_t)(bn + (tid >> 3)) * K + csw * 8;
  const int wrow = wave * 8;     // wave-uniform LDS dest row base per gld16

  const int r7 = l16 & 7;        // read-side swizzle key (tile row & 7 == l16 & 7)

  f32x4 acc[8][4];
#pragma unroll
  for (int i = 0; i < 8; i++)
#pragma unroll
    for (int j = 0; j < 4; j++) acc[i][j] = f32x4{0.f, 0.f, 0.f, 0.f};

#define STAGE8(buf_, tile_, h_) do {                                          \
    const int mat_ = (h_) >> 1;                                               \
    const int r0_  = ((h_) & 1) * 128;                                        \
    const bf16* s_ = (mat_ ? gB : gA) + (size_t)r0_ * K + (size_t)(tile_) * 64; \
    bf16* d_ = &smem[buf_][mat_][r0_ + wrow][0];                              \
    gld16(s_, d_);                                                            \
    gld16(s_ + (size_t)64 * K, d_ + 64 * 64);                                 \
  } while (0)
#define STAGE_ALL(buf_, tile_) do {                                           \
    STAGE8(buf_, tile_, 0); STAGE8(buf_, tile_, 1);                           \
    STAGE8(buf_, tile_, 2); STAGE8(buf_, tile_, 3); } while (0)

  // ---- prologue: stage tile0 + tile1 fully (16 loads); wait tile0 only ----
  STAGE_ALL(0, 0);
  STAGE_ALL(1, 1);
  asm volatile("s_waitcnt vmcnt(8)" ::: "memory");
  asm volatile("s_barrier" ::: "memory");

#pragma unroll 1
  for (int t = 0; t < NTILE; ++t) {
    const int buf = t & 1;
    bf16x8 afX[2][4], bfX[2][4];
    // phase-0 operands (ks=0, mh=0)
#pragma unroll
    for (int nt = 0; nt < 4; nt++)
      bfX[0][nt] = *(const bf16x8*)&smem[buf][1][wn * 64 + nt * 16 + l16][(quad ^ r7) * 8];
#pragma unroll
    for (int i = 0; i < 4; i++)
      afX[0][i] = *(const bf16x8*)&smem[buf][0][wm * 128 + i * 16 + l16][(quad ^ r7) * 8];

#pragma unroll
    for (int ph = 0; ph < 4; ph++) {
      const int mh = ph & 1;          // af buffer in use = mh
      const int ks = ph >> 1;         // bf buffer in use = ks
      // prefetch next phase's frags into the idle register buffer
      if (ph == 0) {
#pragma unroll
        for (int i = 0; i < 4; i++)
          afX[1][i] = *(const bf16x8*)&smem[buf][0][wm * 128 + (4 + i) * 16 + l16][(quad ^ r7) * 8];
      } else if (ph == 1) {
#pragma unroll
        for (int nt = 0; nt < 4; nt++)
          bfX[1][nt] = *(const bf16x8*)&smem[buf][1][wn * 64 + nt * 16 + l16][((4 + quad) ^ r7) * 8];
#pragma unroll
        for (int i = 0; i < 4; i++)
          afX[0][i] = *(const bf16x8*)&smem[buf][0][wm * 128 + i * 16 + l16][((4 + quad) ^ r7) * 8];
      } else if (ph == 2) {
#pragma unroll
        for (int i = 0; i < 4; i++)
          afX[1][i] = *(const bf16x8*)&smem[buf][0][wm * 128 + (4 + i) * 16 + l16][((4 + quad) ^ r7) * 8];
      }
      __builtin_amdgcn_s_setprio(1);
#pragma unroll
      for (int i = 0; i < 4; i++)
#pragma unroll
        for (int nt = 0; nt < 4; nt++)
          acc[mh * 4 + i][nt] =
              __builtin_amdgcn_mfma_f32_16x16x32_bf16(afX[mh][i], bfX[ks][nt], acc[mh * 4 + i][nt], 0, 0, 0);
      __builtin_amdgcn_s_setprio(0);
    }

    // ---- tile boundary: 2 barriers, counted vmcnt (never 0 mid-loop) ----
    if (t + 1 < NTILE) {
      asm volatile("s_barrier" ::: "memory");           // all waves done reading buf
      if (t + 2 < NTILE) {
        STAGE_ALL(buf, t + 2);                          // 8 loads into freed buf
        asm volatile("s_waitcnt vmcnt(8)" ::: "memory");// t+1's 8 drained; t+2 in flight
      } else {
        asm volatile("s_waitcnt vmcnt(0)" ::: "memory");// last tile: full drain
      }
      asm volatile("s_barrier" ::: "memory");           // t+1's LDS visible to all
    }
  }
#undef STAGE_ALL
#undef STAGE8

  // ---- register-only swiglu epilogue: u = acc[mt][ntl], v = acc[mt][ntl+2] ----
  const int cg = (bn >> 1) + wn * 32;
#pragma unroll
  for (int ntl = 0; ntl < 2; ntl++) {
    const float bu = bias[bn + wn * 64 + ntl * 16 + l16];
    const float bv = bias[bn + wn * 64 + 32 + ntl * 16 + l16];
    const int col = cg + ntl * 16 + l16;
#pragma unroll
    for (int mt = 0; mt < 8; mt++) {
      const int row = bm + wm * 128 + mt * 16 + quad * 4;
#pragma unroll
      for (int r = 0; r < 4; r++) {
        float u = acc[mt][ntl][r] + bu;
        float v = acc[mt][ntl + 2][r] + bv;
        float sig = RCPF(1.f + EXP2F(-v * 1.44269504f));
        Cmat[(size_t)(row + r) * 4096 + col] = (bf16)(u * v * sig);
      }
    }
  }
}

// =====================  RMSNorm: fp32 in -> bf16 out (row = 1024)  =====================
__global__ __launch_bounds__(256) void rmsnorm_kernel(const float* __restrict__ X,
                                                      bf16* __restrict__ O) {
  const int row = blockIdx.x;
  const int tid = threadIdx.x;
  const int wave = tid >> 6;
  f32x4 v = *(const f32x4*)(X + (size_t)row * C_ + tid * 4);
  float s = v[0] * v[0] + v[1] * v[1] + v[2] * v[2] + v[3] * v[3];
#pragma unroll
  for (int off = 32; off >= 1; off >>= 1) s += __shfl_xor(s, off);
  __shared__ float wsum[4];
  __shared__ float scale_sh;
  if ((tid & 63) == 0) wsum[wave] = s;
  __syncthreads();
  if (tid == 0)
    scale_sh = rsqrtf((wsum[0] + wsum[1] + wsum[2] + wsum[3]) * (1.f / (float)C_) + 1e-6f);
  __syncthreads();
  const float sc = scale_sh;
  bf16x4 o;
  o[0] = (bf16)(v[0] * sc); o[1] = (bf16)(v[1] * sc);
  o[2] = (bf16)(v[2] * sc); o[3] = (bf16)(v[3] * sc);
  *(bf16x4*)(O + (size_t)row * C_ + tid * 4) = o;
}

// ==========  Rotary on q,k (bf16, in-place) + q0/k0 = sqrt(kc + |.|^2)  ==========
__global__ __launch_bounds__(256) void rotary_kernel(bf16* __restrict__ qkv,
                                                     const float* __restrict__ kcb,
                                                     float* __restrict__ q0b,
                                                     float* __restrict__ k0b) {
  const int wid  = blockIdx.x * 4 + (threadIdx.x >> 6);  // one wave per (b,t,h)
  const int lane = threadIdx.x & 63;
  const int b = wid >> 15;          // T_*H_ = 32768
  const int rem = wid & 32767;
  const int t = rem >> 4;
  const int h = rem & 15;
  const int i = lane & 31;
  const float invf = expf(-((float)i / 32.f) * 9.210340371976184f);  // 10000^(-i/32)
  const float ang = (float)t * invf;
  const float cx = cosf(ang), sx = sinf(ang);
  const float kc = kcb[h];
  bf16* qp = qkv + (size_t)(b * T_ + t) * 3072 + h * 64;

#pragma unroll
  for (int which = 0; which < 2; which++) {
    bf16* p = qp + which * 1024;   // q then k
    float x1 = (float)p[i];
    float x2 = (float)p[i + 32];
    float o = (lane < 32) ? (x1 * cx + x2 * sx) : (x2 * cx - x1 * sx);
    float ss = o * o;
#pragma unroll
    for (int off = 32; off >= 1; off >>= 1) ss += __shfl_xor(ss, off);
    p[lane] = (bf16)o;
    if (lane == 0) {
      float* dst = which == 0 ? q0b : k0b;
      dst[(size_t)(b * H_ + h) * T_ + t] = SQRTF(kc + ss);
    }
  }
}

// =====================  Hyperbolic flash attention (v9)  =====================
// v9: CU-pair-complementary ty remap.  Blocks i and i+256 co-locate on the same CU
// (grid 32x16, x-fastest dispatch, 256%8==0 XCD round-robin).  y<8 -> ty=15-y
// (heavy, dispatched first, LPT), y>=8 -> ty=y-8 -> every CU pair sums to 34 iters.
__global__ __launch_bounds__(512) void attn_kernel(const bf16* __restrict__ qkv,
                                                   const float* __restrict__ q0b,
                                                   const float* __restrict__ k0b,
                                                   const float* __restrict__ kcb,
                                                   bf16* __restrict__ outp) {
  __shared__ __align__(16) bf16 Kls[2][64][72];
  __shared__ __align__(16) bf16 Vt[2][64][68];
  __shared__ __align__(16) bf16 Pls[8][16 * 36];
  __shared__ float k0s[2][64];

  const int tid = threadIdx.x;
  const int wave = tid >> 6, lane = tid & 63;
  const int quad = lane >> 4, l16 = lane & 15;
  const int bh = blockIdx.x;
  const int b = bh >> 4, h = bh & 15;

  const float kc = kcb[h];
  const float inv_kc = 1.f / kc;
  const float sqkc = SQRTF(kc);
  const int role = tid >> 8;            // 0: K crew, 1: V crew
  const int st = tid & 255;
  const int sp = st & 31, dq = st >> 5; // s-pair 0..31, d-chunk 0..7
  bf16* Pl = Pls[wave];
  const float* q0base = q0b + (size_t)(b * H_ + h) * T_;
  const float* k0base = k0b + (size_t)(b * H_ + h) * T_;

  const int yb = (int)blockIdx.y;
  const int ty = (yb < 8) ? (15 - yb) : (yb - 8);  // CU pair (y, y+8): 34 iters const
  const int t0 = ty * 128;
  const int tb = t0 + wave * 16;
  const int nIter = 2 * ty + 2;

  // q A-frags: A[m=l16][k=quad*8+j]
  const bf16* qrow = qkv + (size_t)(b * T_ + tb + l16) * 3072 + h * 64;
  bf16x8 aq0 = *(const bf16x8*)(qrow + quad * 8);
  bf16x8 aq1 = *(const bf16x8*)(qrow + 32 + quad * 8);
  float q0r[4];
#pragma unroll
  for (int r = 0; r < 4; r++) q0r[r] = q0base[tb + quad * 4 + r];

  f32x4 o[4];
#pragma unroll
  for (int dt = 0; dt < 4; dt++) o[dt] = f32x4{0.f, 0.f, 0.f, 0.f};
  float lrow[4] = {0.f, 0.f, 0.f, 0.f};

  // ---- prologue: prefetch tile 0.  role 0 loads K rows (2sp, 2sp+1); role 1 V.
  const bf16* base = qkv + (size_t)b * T_ * 3072 + 1024 + role * 1024 + h * 64 + dq * 8;
  bf16x8 pf_a = *(const bf16x8*)(base + (size_t)(2 * sp) * 3072);
  bf16x8 pf_b = *(const bf16x8*)(base + (size_t)(2 * sp + 1) * 3072);
  float k0v = (tid < 64) ? k0base[tid] : 0.f;

  for (int it = 0; it < nIter; ++it) {
    const int s0 = it * 64;
    const int buf = it & 1;
    // ---- commit prefetched tile ----
    if (role == 0) {
      *(bf16x8*)&Kls[buf][2 * sp][dq * 8]     = pf_a;
      *(bf16x8*)&Kls[buf][2 * sp + 1][dq * 8] = pf_b;
    } else {
#pragma unroll
      for (int i2 = 0; i2 < 8; i2++) {
        bf16x2 pr;
        pr[0] = pf_a[i2];
        pr[1] = pf_b[i2];
        *(bf16x2*)&Vt[buf][dq * 8 + i2][2 * sp] = pr;
      }
    }
    if (tid < 64) k0s[buf][tid] = k0v;
    __syncthreads();

    // ---- prefetch NEXT tile (clamped; latency overlaps compute) ----
    const int s0n = (it + 1 < nIter) ? s0 + 64 : s0;
    pf_a = *(const bf16x8*)(base + (size_t)(s0n + 2 * sp) * 3072);
    pf_b = *(const bf16x8*)(base + (size_t)(s0n + 2 * sp + 1) * 3072);
    if (tid < 64) k0v = k0base[s0n + tid];

    if (s0 <= tb + 15) {   // causal: this wave has live columns in the tile
      // ---- S = q @ K^T (four 16-col n-tiles) ----
      f32x4 sc[4];
#pragma unroll
      for (int nt = 0; nt < 4; nt++) {
        sc[nt] = f32x4{0.f, 0.f, 0.f, 0.f};
        bf16x8 b0 = *(const bf16x8*)&Kls[buf][nt * 16 + l16][quad * 8];
        bf16x8 b1 = *(const bf16x8*)&Kls[buf][nt * 16 + l16][32 + quad * 8];
        sc[nt] = __builtin_amdgcn_mfma_f32_16x16x32_bf16(aq0, b0, sc[nt], 0, 0, 0);
        sc[nt] = __builtin_amdgcn_mfma_f32_16x16x32_bf16(aq1, b1, sc[nt], 0, 0, 0);
      }

      // ---- p = exp(-dis) in two 32-col chunks; P roundtrip per chunk ----
      bf16x8 ap[2];
#pragma unroll
      for (int ck = 0; ck < 2; ck++) {
#pragma unroll
        for (int ntl = 0; ntl < 2; ntl++) {
          const int nt = ck * 2 + ntl;
          const float k0c = k0s[buf][nt * 16 + l16];
          const int s = s0 + nt * 16 + l16;
#pragma unroll
          for (int r = 0; r < 4; r++) {
            const int t = tb + quad * 4 + r;
            float lor = sc[nt][r] - q0r[r] * k0c;
            float ratio = fmaxf(-lor * inv_kc, 1.f + 1e-6f);
            float wv = ratio + SQRTF(ratio * ratio - 1.f);
            float p = EXP2F(-sqkc * LOG2F(wv));
            p = (s <= t) ? p : 0.f;
            lrow[r] += p;
            Pl[(quad * 4 + r) * 36 + ntl * 16 + l16] = (bf16)p;
          }
        }
        ap[ck] = *(const bf16x8*)&Pl[l16 * 36 + quad * 8];
      }
#pragma unroll
      for (int dt = 0; dt < 4; dt++) {
        bf16x8 bv0 = *(const bf16x8*)&Vt[buf][dt * 16 + l16][quad * 8];
        bf16x8 bv1 = *(const bf16x8*)&Vt[buf][dt * 16 + l16][32 + quad * 8];
        o[dt] = __builtin_amdgcn_mfma_f32_16x16x32_bf16(ap[0], bv0, o[dt], 0, 0, 0);
        o[dt] = __builtin_amdgcn_mfma_f32_16x16x32_bf16(ap[1], bv1, o[dt], 0, 0, 0);
      }
    }
  }

  // ---- one deferred l-reduction over the 16 l16 lanes, then write O ----
#pragma unroll
  for (int r = 0; r < 4; r++) {
#pragma unroll
    for (int off = 1; off <= 8; off <<= 1) lrow[r] += __shfl_xor(lrow[r], off);
  }
#pragma unroll
  for (int r = 0; r < 4; r++) {
    const float invl = RCPF(lrow[r]);
    const int t = tb + quad * 4 + r;
#pragma unroll
    for (int dt = 0; dt < 4; dt++) {
      float val = o[dt][r] * invl;
      outp[(size_t)(b * T_ + t) * C_ + h * 64 + dt * 16 + l16] = (bf16)val;
    }
  }
}

// =====================  host-side launch  =====================
extern "C" void kernel_launch(void* const* d_in, const int* in_sizes, int n_in,
                              void* d_out, int out_size, void* d_ws, size_t ws_size,
                              hipStream_t stream) {
  const float* x      = (const float*)d_in[0];
  const float* w_qkv  = (const float*)d_in[1];
  const float* w_out  = (const float*)d_in[2];
  const float* kcb    = (const float*)d_in[3];
  const float* w_uv   = (const float*)d_in[4];
  const float* b_uv   = (const float*)d_in[5];
  const float* w_mlp  = (const float*)d_in[6];
  const float* b_mlp  = (const float*)d_in[7];
  float* out = (float*)d_out;

  const size_t MB = 1024ull * 1024ull;
  char* w = (char*)d_ws;
  bf16*  wqkv_b  = (bf16*)(w + 0);          //  6 MB   [0,6)
  bf16*  wout_b  = (bf16*)(w + 6 * MB);     //  2 MB   [6,8)
  bf16*  wuv_p   = (bf16*)(w + 8 * MB);     // 16 MB   [8,24)  row-permuted {32u,32v}/64
  bf16*  wmlp_b  = (bf16*)(w + 24 * MB);    //  8 MB   [24,32)
  bf16*  hbuf    = (bf16*)(w + 32 * MB);    //  8 MB   [32,40)
  bf16*  qkvbuf  = (bf16*)(w + 40 * MB);    // 24 MB   [40,64) dead after attn
  bf16*  attnbuf = (bf16*)(w + 64 * MB);    //  8 MB   [64,72) dead after wout GEMM
  bf16*  gbuf    = (bf16*)(w + 40 * MB);    // 32 MB   [40,72) over qkv+attn (step 7)
  float* x2buf   = (float*)(w + 72 * MB);   // 16 MB   [72,88) fp32
  float* q0b     = (float*)(w + 88 * MB);                 // 256 KB
  float* k0b     = (float*)(w + 88 * MB + 256 * 1024);    // 256 KB
  float* biasp   = (float*)(w + 88 * MB + 512 * 1024);    //  32 KB (permuted b_uv)
  // total: ~88.6 MB

  // 0) weight casts (+w_uv/b_uv row permutation), single launch
  const int total4 = 786432 + 262144 + 2097152 + 1048576 + 2048;
  cast_all_kernel<<<(total4 + 255) / 256, 256, 0, stream>>>(
      w_qkv, w_out, w_uv, w_mlp, b_uv, wqkv_b, wout_b, wuv_p, wmlp_b, biasp);

  // 1) h = rmsnorm(x)
  rmsnorm_kernel<<<M_, 256, 0, stream>>>(x, hbuf);
  // 2) qkv = h @ w_qkv^T   (128^2 free-run, 768 blocks, 2 resident/CU)
  gemm_fr<0, bf16, 128><<<dim3(M_ / 128, 3072 / 128), 256, 0, stream>>>(
      hbuf, wqkv_b, qkvbuf, nullptr, nullptr, 3072, 1024);
  // 3) rotary(q,k) in-place + q0/k0
  rotary_kernel<<<(B_ * T_ * H_) / 4, 256, 0, stream>>>(qkvbuf, kcb, q0b, k0b);
  // 4) hyperbolic flash attention (v9: balanced CU pairs)
  attn_kernel<<<dim3(B_ * H_, 16), 512, 0, stream>>>(qkvbuf, q0b, k0b, kcb, attnbuf);
  // 5) x2 = x + attn @ w_out^T   (128x64 free-run, 512 blocks = 2/CU)
  gemm_fr<1, float, 64><<<dim3(M_ / 128, 1024 / 64), 256, 0, stream>>>(
      attnbuf, wout_b, x2buf, nullptr, x, 1024, 1024);
  // 6) h2 = rmsnorm(x2)
  rmsnorm_kernel<<<M_, 256, 0, stream>>>(x2buf, hbuf);
  // 7) g = swiglu(h2 @ w_uv_p^T + b_uv_p) -> 4096-col bf16  (256^2, R5 structure)
  gemm8_swiglu<<<dim3(M_ / 256, 8192 / 256), 512, 0, stream>>>(hbuf, wuv_p, gbuf, biasp);
  // 8) out = x2 + g @ w_mlp^T + b_mlp   (128x64 free-run, K=4096, 512 blocks = 2/CU)
  gemm_fr<3, float, 64><<<dim3(M_ / 128, 1024 / 64), 256, 0, stream>>>(
      gbuf, wmlp_b, out, b_mlp, x2buf, 1024, 4096);
}

// Round 9
// 380.455 us; speedup vs baseline: 1.0223x; 1.0070x over previous
//
#include <hip/hip_runtime.h>
#include <cstdint>
#include <cmath>

typedef __bf16 bf16;
typedef __attribute__((ext_vector_type(8))) __bf16 bf16x8;
typedef __attribute__((ext_vector_type(4))) __bf16 bf16x4;
typedef __attribute__((ext_vector_type(2))) __bf16 bf16x2;
typedef __attribute__((ext_vector_type(4))) float f32x4;

constexpr int B_ = 2, T_ = 2048, C_ = 1024, H_ = 16, HD_ = 64;
constexpr int M_ = B_ * T_;   // 4096

#define EXP2F(x) __builtin_amdgcn_exp2f(x)
#define LOG2F(x) __builtin_amdgcn_logf(x)
#define SQRTF(x) __builtin_amdgcn_sqrtf(x)
#define RCPF(x)  __builtin_amdgcn_rcpf(x)

// ---- async global->LDS, 16B per lane; LDS dest = wave-uniform base + lane*16 ----
__device__ __forceinline__ void gld16(const void* g, void* l) {
  __builtin_amdgcn_global_load_lds((const __attribute__((address_space(1))) void*)g,
                                   (__attribute__((address_space(3))) void*)l, 16, 0, 0);
}

// ============  fused weight cast fp32 -> bf16 (w_uv/b_uv row-PERMUTED)  ============
// Permutation (for the 256^2 swiglu GEMM): 64-row groups of {32 u, 32 v}:
//   perm row 64g+i = u[32g+i]      (i < 32)
//                  = v[32g+i-32]   (i >= 32)
__global__ __launch_bounds__(256) void cast_all_kernel(const float* __restrict__ s0,
                                                       const float* __restrict__ s1,
                                                       const float* __restrict__ s2,
                                                       const float* __restrict__ s3,
                                                       const float* __restrict__ s4,
                                                       bf16* __restrict__ d0,
                                                       bf16* __restrict__ d1,
                                                       bf16* __restrict__ d2,
                                                       bf16* __restrict__ d3,
                                                       float* __restrict__ d4) {
  size_t gid = (size_t)blockIdx.x * 256 + threadIdx.x;
  if (gid >= 786432 + 262144 + 2097152 + 1048576) {
    size_t g4 = gid - (786432 + 262144 + 2097152 + 1048576);
    if (g4 >= 2048) return;
    int r = (int)(g4 * 4);
    int dr;
    if (r < 4096) { int g = r >> 5, i = r & 31; dr = g * 64 + i; }
    else { int j = r - 4096; int g = j >> 5, i = j & 31; dr = g * 64 + 32 + i; }
    *(f32x4*)(d4 + dr) = *(const f32x4*)(s4 + r);
    return;
  }
  const float* src;
  bf16* dst;
  size_t dstoff;
  if (gid < 786432) { src = s0; dst = d0; dstoff = gid * 4; }
  else if (gid < 786432 + 262144) { gid -= 786432; src = s1; dst = d1; dstoff = gid * 4; }
  else if (gid < 786432 + 262144 + 2097152) {
    gid -= 786432 + 262144; src = s2; dst = d2;
    size_t elem = gid * 4;
    int r = (int)(elem >> 10), c = (int)(elem & 1023);
    int dr;
    if (r < 4096) { int g = r >> 5, i = r & 31; dr = g * 64 + i; }
    else { int j = r - 4096; int g = j >> 5, i = j & 31; dr = g * 64 + 32 + i; }
    dstoff = ((size_t)dr << 10) | (size_t)c;
  }
  else { gid -= 786432 + 262144 + 2097152; src = s3; dst = d3; dstoff = gid * 4; }
  f32x4 v = *(const f32x4*)(src + gid * 4);
  bf16x4 o;
  o[0] = (bf16)v[0]; o[1] = (bf16)v[1]; o[2] = (bf16)v[2]; o[3] = (bf16)v[3];
  *(bf16x4*)(dst + dstoff) = o;
}

// =============  128xBN free-running GEMM: C = A @ Bw^T (+bias)(+residual)  =============
// Verified counted-vmcnt 2-barrier/tile schedule (R3-R5), 16x16x32 MFMA.
// BN=128: 8 loads/tile, vmcnt(8).  BN=64: 6 loads/tile, vmcnt(6), 48 KB LDS.
// MODE 0: C=AB  1: +R  2: +bias  3: +bias+R
template <int MODE, typename OutT, int BN = 128>
__global__ __launch_bounds__(256, 2) void gemm_fr(const bf16* __restrict__ A,
                                                  const bf16* __restrict__ Bw,
                                                  OutT* __restrict__ Cmat,
                                                  const float* __restrict__ bias,
                                                  const float* __restrict__ R,
                                                  int N, int K) {
  constexpr int NTN = BN / 32;            // n-tiles per wave (4 or 2)
  __shared__ __align__(16) bf16 smA[2][128][64];
  __shared__ __align__(16) bf16 smB[2][BN][64];

  const int tid  = threadIdx.x;
  const int wave = tid >> 6, lane = tid & 63;
  const int quad = lane >> 4, l16 = lane & 15;
  const int wm = wave >> 1, wn = wave & 1;
  const int bm = blockIdx.x * 128;
  const int bn = blockIdx.y * BN;

  // staging: thread -> row (tid>>3) of a 32-row group, 16B chunk (tid&7); source
  // chunk inverse-swizzled (chunk ^ row&7) so linear gld16 dest + swizzled ds_read
  // compose to identity.
  const int csw = (tid & 7) ^ ((tid >> 3) & 7);
  const bf16* gA = A  + (size_t)(bm + (tid >> 3)) * K + csw * 8;
  const bf16* gB = Bw + (size_t)(bn + (tid >> 3)) * K + csw * 8;
  const int wrow = wave * 8;     // wave-uniform LDS dest row base per gld16
  const int r7 = l16 & 7;        // read-side swizzle key

  f32x4 acc[4][NTN];
#pragma unroll
  for (int i = 0; i < 4; i++)
#pragma unroll
    for (int j = 0; j < NTN; j++) acc[i][j] = f32x4{0.f, 0.f, 0.f, 0.f};

#define STG_ALL(buf_, tile_) do {                                              \
    _Pragma("unroll")                                                          \
    for (int g = 0; g < 4; g++)                                                \
      gld16(gA + (size_t)(g * 32) * K + (size_t)(tile_) * 64,                  \
            &smA[buf_][g * 32 + wrow][0]);                                     \
    _Pragma("unroll")                                                          \
    for (int g = 0; g < BN / 32; g++)                                          \
      gld16(gB + (size_t)(g * 32) * K + (size_t)(tile_) * 64,                  \
            &smB[buf_][g * 32 + wrow][0]);                                     \
  } while (0)

  const int NT = K >> 6;
  // ---- prologue: stage tile0 + tile1; counted wait for tile0 only ----
  STG_ALL(0, 0);
  STG_ALL(1, 1);
  if (BN == 128) asm volatile("s_waitcnt vmcnt(8)" ::: "memory");
  else           asm volatile("s_waitcnt vmcnt(6)" ::: "memory");
  asm volatile("s_barrier" ::: "memory");

#pragma unroll 1
  for (int t = 0; t < NT; ++t) {
    const int buf = t & 1;
    bf16x8 af[2][4], bfr[2][NTN];
    // ks=0 operands
#pragma unroll
    for (int nt = 0; nt < NTN; nt++)
      bfr[0][nt] = *(const bf16x8*)&smB[buf][wn * (BN / 2) + nt * 16 + l16][(quad ^ r7) * 8];
#pragma unroll
    for (int i = 0; i < 4; i++)
      af[0][i] = *(const bf16x8*)&smA[buf][wm * 64 + i * 16 + l16][(quad ^ r7) * 8];
    // prefetch ks=1 operands
#pragma unroll
    for (int nt = 0; nt < NTN; nt++)
      bfr[1][nt] = *(const bf16x8*)&smB[buf][wn * (BN / 2) + nt * 16 + l16][((4 + quad) ^ r7) * 8];
#pragma unroll
    for (int i = 0; i < 4; i++)
      af[1][i] = *(const bf16x8*)&smA[buf][wm * 64 + i * 16 + l16][((4 + quad) ^ r7) * 8];

    __builtin_amdgcn_s_setprio(1);
#pragma unroll
    for (int i = 0; i < 4; i++)
#pragma unroll
      for (int nt = 0; nt < NTN; nt++)
        acc[i][nt] = __builtin_amdgcn_mfma_f32_16x16x32_bf16(af[0][i], bfr[0][nt], acc[i][nt], 0, 0, 0);
    __builtin_amdgcn_s_setprio(0);
    __builtin_amdgcn_s_setprio(1);
#pragma unroll
    for (int i = 0; i < 4; i++)
#pragma unroll
      for (int nt = 0; nt < NTN; nt++)
        acc[i][nt] = __builtin_amdgcn_mfma_f32_16x16x32_bf16(af[1][i], bfr[1][nt], acc[i][nt], 0, 0, 0);
    __builtin_amdgcn_s_setprio(0);

    // ---- tile boundary: 2 barriers, counted vmcnt (never 0 mid-loop) ----
    if (t + 1 < NT) {
      asm volatile("s_barrier" ::: "memory");            // all waves done reading buf
      if (t + 2 < NT) {
        STG_ALL(buf, t + 2);                             // loads into freed buf
        if (BN == 128) asm volatile("s_waitcnt vmcnt(8)" ::: "memory");
        else           asm volatile("s_waitcnt vmcnt(6)" ::: "memory");
      } else {
        asm volatile("s_waitcnt vmcnt(0)" ::: "memory");
      }
      asm volatile("s_barrier" ::: "memory");            // t+1's LDS visible to all
    }
  }
#undef STG_ALL

#pragma unroll
  for (int mt = 0; mt < 4; mt++) {
    const int row = bm + wm * 64 + mt * 16 + quad * 4;
#pragma unroll
    for (int nt = 0; nt < NTN; nt++) {
      const int col = bn + wn * (BN / 2) + nt * 16 + l16;
      float bval = 0.f;
      if (MODE & 2) bval = bias[col];
#pragma unroll
      for (int r = 0; r < 4; r++) {
        float v = acc[mt][nt][r] + bval;
        if (MODE & 1) v += R[(size_t)(row + r) * N + col];
        Cmat[(size_t)(row + r) * N + col] = (OutT)v;
      }
    }
  }
}

// =====================  256x256 plain GEMM (qkv): C = A @ Bw^T, bf16 out  =====================
// Clone of the verified gemm8 core (same staging, T2 swizzle, counted-vmcnt
// 2-barrier/tile schedule, T5 setprio) with a plain store epilogue and runtime N.
// For qkv (M=4096, N=3072): grid 16x12 = 192 blocks = ONE round at 1 block/CU
// (~36.7 us measured per round via gemm8's 512-block / 73.4 us datum).
__global__ __launch_bounds__(512, 2) void gemm256n(const bf16* __restrict__ A,
                                                   const bf16* __restrict__ Bw,
                                                   bf16* __restrict__ Cmat,
                                                   int N) {
  constexpr int K = 1024, NTILE = K / 64;   // 16 K-tiles
  __shared__ __align__(16) bf16 smem[2][2][256][64];   // [buf][A=0/B=1][row][k]

  const int tid  = threadIdx.x;
  const int wave = tid >> 6, lane = tid & 63;
  const int quad = lane >> 4, l16 = lane & 15;
  const int wm = wave >> 2, wn = wave & 3;
  const int bm = blockIdx.x * 256;
  const int bn = blockIdx.y * 256;

  const int csw = (tid & 7) ^ ((tid >> 3) & 7);
  const bf16* gA = A  + (size_t)(bm + (tid >> 3)) * K + csw * 8;
  const bf16* gB = Bw + (size_t)(bn + (tid >> 3)) * K + csw * 8;
  const int wrow = wave * 8;
  const int r7 = l16 & 7;

  f32x4 acc[8][4];
#pragma unroll
  for (int i = 0; i < 8; i++)
#pragma unroll
    for (int j = 0; j < 4; j++) acc[i][j] = f32x4{0.f, 0.f, 0.f, 0.f};

#define STAGE8(buf_, tile_, h_) do {                                          \
    const int mat_ = (h_) >> 1;                                               \
    const int r0_  = ((h_) & 1) * 128;                                        \
    const bf16* s_ = (mat_ ? gB : gA) + (size_t)r0_ * K + (size_t)(tile_) * 64; \
    bf16* d_ = &smem[buf_][mat_][r0_ + wrow][0];                              \
    gld16(s_, d_);                                                            \
    gld16(s_ + (size_t)64 * K, d_ + 64 * 64);                                 \
  } while (0)
#define STAGE_ALL(buf_, tile_) do {                                           \
    STAGE8(buf_, tile_, 0); STAGE8(buf_, tile_, 1);                           \
    STAGE8(buf_, tile_, 2); STAGE8(buf_, tile_, 3); } while (0)

  STAGE_ALL(0, 0);
  STAGE_ALL(1, 1);
  asm volatile("s_waitcnt vmcnt(8)" ::: "memory");
  asm volatile("s_barrier" ::: "memory");

#pragma unroll 1
  for (int t = 0; t < NTILE; ++t) {
    const int buf = t & 1;
    bf16x8 afX[2][4], bfX[2][4];
#pragma unroll
    for (int nt = 0; nt < 4; nt++)
      bfX[0][nt] = *(const bf16x8*)&smem[buf][1][wn * 64 + nt * 16 + l16][(quad ^ r7) * 8];
#pragma unroll
    for (int i = 0; i < 4; i++)
      afX[0][i] = *(const bf16x8*)&smem[buf][0][wm * 128 + i * 16 + l16][(quad ^ r7) * 8];

#pragma unroll
    for (int ph = 0; ph < 4; ph++) {
      const int mh = ph & 1;
      const int ks = ph >> 1;
      if (ph == 0) {
#pragma unroll
        for (int i = 0; i < 4; i++)
          afX[1][i] = *(const bf16x8*)&smem[buf][0][wm * 128 + (4 + i) * 16 + l16][(quad ^ r7) * 8];
      } else if (ph == 1) {
#pragma unroll
        for (int nt = 0; nt < 4; nt++)
          bfX[1][nt] = *(const bf16x8*)&smem[buf][1][wn * 64 + nt * 16 + l16][((4 + quad) ^ r7) * 8];
#pragma unroll
        for (int i = 0; i < 4; i++)
          afX[0][i] = *(const bf16x8*)&smem[buf][0][wm * 128 + i * 16 + l16][((4 + quad) ^ r7) * 8];
      } else if (ph == 2) {
#pragma unroll
        for (int i = 0; i < 4; i++)
          afX[1][i] = *(const bf16x8*)&smem[buf][0][wm * 128 + (4 + i) * 16 + l16][((4 + quad) ^ r7) * 8];
      }
      __builtin_amdgcn_s_setprio(1);
#pragma unroll
      for (int i = 0; i < 4; i++)
#pragma unroll
        for (int nt = 0; nt < 4; nt++)
          acc[mh * 4 + i][nt] =
              __builtin_amdgcn_mfma_f32_16x16x32_bf16(afX[mh][i], bfX[ks][nt], acc[mh * 4 + i][nt], 0, 0, 0);
      __builtin_amdgcn_s_setprio(0);
    }

    if (t + 1 < NTILE) {
      asm volatile("s_barrier" ::: "memory");
      if (t + 2 < NTILE) {
        STAGE_ALL(buf, t + 2);
        asm volatile("s_waitcnt vmcnt(8)" ::: "memory");
      } else {
        asm volatile("s_waitcnt vmcnt(0)" ::: "memory");
      }
      asm volatile("s_barrier" ::: "memory");
    }
  }
#undef STAGE_ALL
#undef STAGE8

  // ---- plain bf16 store epilogue ----
#pragma unroll
  for (int mt = 0; mt < 8; mt++) {
    const int row = bm + wm * 128 + mt * 16 + quad * 4;
#pragma unroll
    for (int nt = 0; nt < 4; nt++) {
      const int col = bn + wn * 64 + nt * 16 + l16;
#pragma unroll
      for (int r = 0; r < 4; r++)
        Cmat[(size_t)(row + r) * N + col] = (bf16)acc[mt][nt][r];
    }
  }
}

// =====================  256x256 GEMM + swiglu epilogue (R5 structure)  =====================
// Structure at its measured ceiling for K=1024 (~930 TF): full-tile LDS double
// buffer, 2 barriers/tile, counted vmcnt (never 0 mid-loop), reg-dbuf phase
// pipeline, T2 3-bit chunk swizzle (bank-conflict == 0), T5 setprio, 16x16x32.
__global__ __launch_bounds__(512, 2) void gemm8_swiglu(const bf16* __restrict__ A,
                                                       const bf16* __restrict__ Bw,
                                                       bf16* __restrict__ Cmat,
                                                       const float* __restrict__ bias) {
  constexpr int K = 1024, NTILE = K / 64;   // 16 K-tiles
  __shared__ __align__(16) bf16 smem[2][2][256][64];   // [buf][A=0/B=1][row][k]

  const int tid  = threadIdx.x;
  const int wave = tid >> 6, lane = tid & 63;
  const int quad = lane >> 4, l16 = lane & 15;
  const int wm = wave >> 2, wn = wave & 3;
  const int bm = blockIdx.x * 256;
  const int bn = blockIdx.y * 256;

  const int csw = (tid & 7) ^ ((tid >> 3) & 7);
  const bf16* gA = A  + (size_t)(bm + (tid >> 3)) * K + csw * 8;
  const bf16* gB = Bw + (size_t)(bn + (tid >> 3)) * K + csw * 8;
  const int wrow = wave * 8;     // wave-uniform LDS dest row base per gld16

  const int r7 = l16 & 7;        // read-side swizzle key (tile row & 7 == l16 & 7)

  f32x4 acc[8][4];
#pragma unroll
  for (int i = 0; i < 8; i++)
#pragma unroll
    for (int j = 0; j < 4; j++) acc[i][j] = f32x4{0.f, 0.f, 0.f, 0.f};

#define STAGE8(buf_, tile_, h_) do {                                          \
    const int mat_ = (h_) >> 1;                                               \
    const int r0_  = ((h_) & 1) * 128;                                        \
    const bf16* s_ = (mat_ ? gB : gA) + (size_t)r0_ * K + (size_t)(tile_) * 64; \
    bf16* d_ = &smem[buf_][mat_][r0_ + wrow][0];                              \
    gld16(s_, d_);                                                            \
    gld16(s_ + (size_t)64 * K, d_ + 64 * 64);                                 \
  } while (0)
#define STAGE_ALL(buf_, tile_) do {                                           \
    STAGE8(buf_, tile_, 0); STAGE8(buf_, tile_, 1);                           \
    STAGE8(buf_, tile_, 2); STAGE8(buf_, tile_, 3); } while (0)

  // ---- prologue: stage tile0 + tile1 fully (16 loads); wait tile0 only ----
  STAGE_ALL(0, 0);
  STAGE_ALL(1, 1);
  asm volatile("s_waitcnt vmcnt(8)" ::: "memory");
  asm volatile("s_barrier" ::: "memory");

#pragma unroll 1
  for (int t = 0; t < NTILE; ++t) {
    const int buf = t & 1;
    bf16x8 afX[2][4], bfX[2][4];
    // phase-0 operands (ks=0, mh=0)
#pragma unroll
    for (int nt = 0; nt < 4; nt++)
      bfX[0][nt] = *(const bf16x8*)&smem[buf][1][wn * 64 + nt * 16 + l16][(quad ^ r7) * 8];
#pragma unroll
    for (int i = 0; i < 4; i++)
      afX[0][i] = *(const bf16x8*)&smem[buf][0][wm * 128 + i * 16 + l16][(quad ^ r7) * 8];

#pragma unroll
    for (int ph = 0; ph < 4; ph++) {
      const int mh = ph & 1;          // af buffer in use = mh
      const int ks = ph >> 1;         // bf buffer in use = ks
      // prefetch next phase's frags into the idle register buffer
      if (ph == 0) {
#pragma unroll
        for (int i = 0; i < 4; i++)
          afX[1][i] = *(const bf16x8*)&smem[buf][0][wm * 128 + (4 + i) * 16 + l16][(quad ^ r7) * 8];
      } else if (ph == 1) {
#pragma unroll
        for (int nt = 0; nt < 4; nt++)
          bfX[1][nt] = *(const bf16x8*)&smem[buf][1][wn * 64 + nt * 16 + l16][((4 + quad) ^ r7) * 8];
#pragma unroll
        for (int i = 0; i < 4; i++)
          afX[0][i] = *(const bf16x8*)&smem[buf][0][wm * 128 + i * 16 + l16][((4 + quad) ^ r7) * 8];
      } else if (ph == 2) {
#pragma unroll
        for (int i = 0; i < 4; i++)
          afX[1][i] = *(const bf16x8*)&smem[buf][0][wm * 128 + (4 + i) * 16 + l16][((4 + quad) ^ r7) * 8];
      }
      __builtin_amdgcn_s_setprio(1);
#pragma unroll
      for (int i = 0; i < 4; i++)
#pragma unroll
        for (int nt = 0; nt < 4; nt++)
          acc[mh * 4 + i][nt] =
              __builtin_amdgcn_mfma_f32_16x16x32_bf16(afX[mh][i], bfX[ks][nt], acc[mh * 4 + i][nt], 0, 0, 0);
      __builtin_amdgcn_s_setprio(0);
    }

    // ---- tile boundary: 2 barriers, counted vmcnt (never 0 mid-loop) ----
    if (t + 1 < NTILE) {
      asm volatile("s_barrier" ::: "memory");           // all waves done reading buf
      if (t + 2 < NTILE) {
        STAGE_ALL(buf, t + 2);                          // 8 loads into freed buf
        asm volatile("s_waitcnt vmcnt(8)" ::: "memory");// t+1's 8 drained; t+2 in flight
      } else {
        asm volatile("s_waitcnt vmcnt(0)" ::: "memory");// last tile: full drain
      }
      asm volatile("s_barrier" ::: "memory");           // t+1's LDS visible to all
    }
  }
#undef STAGE_ALL
#undef STAGE8

  // ---- register-only swiglu epilogue: u = acc[mt][ntl], v = acc[mt][ntl+2] ----
  const int cg = (bn >> 1) + wn * 32;
#pragma unroll
  for (int ntl = 0; ntl < 2; ntl++) {
    const float bu = bias[bn + wn * 64 + ntl * 16 + l16];
    const float bv = bias[bn + wn * 64 + 32 + ntl * 16 + l16];
    const int col = cg + ntl * 16 + l16;
#pragma unroll
    for (int mt = 0; mt < 8; mt++) {
      const int row = bm + wm * 128 + mt * 16 + quad * 4;
#pragma unroll
      for (int r = 0; r < 4; r++) {
        float u = acc[mt][ntl][r] + bu;
        float v = acc[mt][ntl + 2][r] + bv;
        float sig = RCPF(1.f + EXP2F(-v * 1.44269504f));
        Cmat[(size_t)(row + r) * 4096 + col] = (bf16)(u * v * sig);
      }
    }
  }
}

// =====================  RMSNorm: fp32 in -> bf16 out (row = 1024)  =====================
__global__ __launch_bounds__(256) void rmsnorm_kernel(const float* __restrict__ X,
                                                      bf16* __restrict__ O) {
  const int row = blockIdx.x;
  const int tid = threadIdx.x;
  const int wave = tid >> 6;
  f32x4 v = *(const f32x4*)(X + (size_t)row * C_ + tid * 4);
  float s = v[0] * v[0] + v[1] * v[1] + v[2] * v[2] + v[3] * v[3];
#pragma unroll
  for (int off = 32; off >= 1; off >>= 1) s += __shfl_xor(s, off);
  __shared__ float wsum[4];
  __shared__ float scale_sh;
  if ((tid & 63) == 0) wsum[wave] = s;
  __syncthreads();
  if (tid == 0)
    scale_sh = rsqrtf((wsum[0] + wsum[1] + wsum[2] + wsum[3]) * (1.f / (float)C_) + 1e-6f);
  __syncthreads();
  const float sc = scale_sh;
  bf16x4 o;
  o[0] = (bf16)(v[0] * sc); o[1] = (bf16)(v[1] * sc);
  o[2] = (bf16)(v[2] * sc); o[3] = (bf16)(v[3] * sc);
  *(bf16x4*)(O + (size_t)row * C_ + tid * 4) = o;
}

// ==========  Rotary on q,k (bf16, in-place) + q0/k0 = sqrt(kc + |.|^2)  ==========
__global__ __launch_bounds__(256) void rotary_kernel(bf16* __restrict__ qkv,
                                                     const float* __restrict__ kcb,
                                                     float* __restrict__ q0b,
                                                     float* __restrict__ k0b) {
  const int wid  = blockIdx.x * 4 + (threadIdx.x >> 6);  // one wave per (b,t,h)
  const int lane = threadIdx.x & 63;
  const int b = wid >> 15;          // T_*H_ = 32768
  const int rem = wid & 32767;
  const int t = rem >> 4;
  const int h = rem & 15;
  const int i = lane & 31;
  const float invf = expf(-((float)i / 32.f) * 9.210340371976184f);  // 10000^(-i/32)
  const float ang = (float)t * invf;
  const float cx = cosf(ang), sx = sinf(ang);
  const float kc = kcb[h];
  bf16* qp = qkv + (size_t)(b * T_ + t) * 3072 + h * 64;

#pragma unroll
  for (int which = 0; which < 2; which++) {
    bf16* p = qp + which * 1024;   // q then k
    float x1 = (float)p[i];
    float x2 = (float)p[i + 32];
    float o = (lane < 32) ? (x1 * cx + x2 * sx) : (x2 * cx - x1 * sx);
    float ss = o * o;
#pragma unroll
    for (int off = 32; off >= 1; off >>= 1) ss += __shfl_xor(ss, off);
    p[lane] = (bf16)o;
    if (lane == 0) {
      float* dst = which == 0 ? q0b : k0b;
      dst[(size_t)(b * H_ + h) * T_ + t] = SQRTF(kc + ss);
    }
  }
}

// =====================  Hyperbolic flash attention (v9)  =====================
// v9: CU-pair-complementary ty remap.  Blocks i and i+256 co-locate on the same CU
// (grid 32x16, x-fastest dispatch, 256%8==0 XCD round-robin).  y<8 -> ty=15-y
// (heavy, dispatched first, LPT), y>=8 -> ty=y-8 -> every CU pair sums to 34 iters.
__global__ __launch_bounds__(512) void attn_kernel(const bf16* __restrict__ qkv,
                                                   const float* __restrict__ q0b,
                                                   const float* __restrict__ k0b,
                                                   const float* __restrict__ kcb,
                                                   bf16* __restrict__ outp) {
  __shared__ __align__(16) bf16 Kls[2][64][72];
  __shared__ __align__(16) bf16 Vt[2][64][68];
  __shared__ __align__(16) bf16 Pls[8][16 * 36];
  __shared__ float k0s[2][64];

  const int tid = threadIdx.x;
  const int wave = tid >> 6, lane = tid & 63;
  const int quad = lane >> 4, l16 = lane & 15;
  const int bh = blockIdx.x;
  const int b = bh >> 4, h = bh & 15;

  const float kc = kcb[h];
  const float inv_kc = 1.f / kc;
  const float sqkc = SQRTF(kc);
  const int role = tid >> 8;            // 0: K crew, 1: V crew
  const int st = tid & 255;
  const int sp = st & 31, dq = st >> 5; // s-pair 0..31, d-chunk 0..7
  bf16* Pl = Pls[wave];
  const float* q0base = q0b + (size_t)(b * H_ + h) * T_;
  const float* k0base = k0b + (size_t)(b * H_ + h) * T_;

  const int yb = (int)blockIdx.y;
  const int ty = (yb < 8) ? (15 - yb) : (yb - 8);  // CU pair (y, y+8): 34 iters const
  const int t0 = ty * 128;
  const int tb = t0 + wave * 16;
  const int nIter = 2 * ty + 2;

  // q A-frags: A[m=l16][k=quad*8+j]
  const bf16* qrow = qkv + (size_t)(b * T_ + tb + l16) * 3072 + h * 64;
  bf16x8 aq0 = *(const bf16x8*)(qrow + quad * 8);
  bf16x8 aq1 = *(const bf16x8*)(qrow + 32 + quad * 8);
  float q0r[4];
#pragma unroll
  for (int r = 0; r < 4; r++) q0r[r] = q0base[tb + quad * 4 + r];

  f32x4 o[4];
#pragma unroll
  for (int dt = 0; dt < 4; dt++) o[dt] = f32x4{0.f, 0.f, 0.f, 0.f};
  float lrow[4] = {0.f, 0.f, 0.f, 0.f};

  // ---- prologue: prefetch tile 0.  role 0 loads K rows (2sp, 2sp+1); role 1 V.
  const bf16* base = qkv + (size_t)b * T_ * 3072 + 1024 + role * 1024 + h * 64 + dq * 8;
  bf16x8 pf_a = *(const bf16x8*)(base + (size_t)(2 * sp) * 3072);
  bf16x8 pf_b = *(const bf16x8*)(base + (size_t)(2 * sp + 1) * 3072);
  float k0v = (tid < 64) ? k0base[tid] : 0.f;

  for (int it = 0; it < nIter; ++it) {
    const int s0 = it * 64;
    const int buf = it & 1;
    // ---- commit prefetched tile ----
    if (role == 0) {
      *(bf16x8*)&Kls[buf][2 * sp][dq * 8]     = pf_a;
      *(bf16x8*)&Kls[buf][2 * sp + 1][dq * 8] = pf_b;
    } else {
#pragma unroll
      for (int i2 = 0; i2 < 8; i2++) {
        bf16x2 pr;
        pr[0] = pf_a[i2];
        pr[1] = pf_b[i2];
        *(bf16x2*)&Vt[buf][dq * 8 + i2][2 * sp] = pr;
      }
    }
    if (tid < 64) k0s[buf][tid] = k0v;
    __syncthreads();

    // ---- prefetch NEXT tile (clamped; latency overlaps compute) ----
    const int s0n = (it + 1 < nIter) ? s0 + 64 : s0;
    pf_a = *(const bf16x8*)(base + (size_t)(s0n + 2 * sp) * 3072);
    pf_b = *(const bf16x8*)(base + (size_t)(s0n + 2 * sp + 1) * 3072);
    if (tid < 64) k0v = k0base[s0n + tid];

    if (s0 <= tb + 15) {   // causal: this wave has live columns in the tile
      // ---- S = q @ K^T (four 16-col n-tiles) ----
      f32x4 sc[4];
#pragma unroll
      for (int nt = 0; nt < 4; nt++) {
        sc[nt] = f32x4{0.f, 0.f, 0.f, 0.f};
        bf16x8 b0 = *(const bf16x8*)&Kls[buf][nt * 16 + l16][quad * 8];
        bf16x8 b1 = *(const bf16x8*)&Kls[buf][nt * 16 + l16][32 + quad * 8];
        sc[nt] = __builtin_amdgcn_mfma_f32_16x16x32_bf16(aq0, b0, sc[nt], 0, 0, 0);
        sc[nt] = __builtin_amdgcn_mfma_f32_16x16x32_bf16(aq1, b1, sc[nt], 0, 0, 0);
      }

      // ---- p = exp(-dis) in two 32-col chunks; P roundtrip per chunk ----
      bf16x8 ap[2];
#pragma unroll
      for (int ck = 0; ck < 2; ck++) {
#pragma unroll
        for (int ntl = 0; ntl < 2; ntl++) {
          const int nt = ck * 2 + ntl;
          const float k0c = k0s[buf][nt * 16 + l16];
          const int s = s0 + nt * 16 + l16;
#pragma unroll
          for (int r = 0; r < 4; r++) {
            const int t = tb + quad * 4 + r;
            float lor = sc[nt][r] - q0r[r] * k0c;
            float ratio = fmaxf(-lor * inv_kc, 1.f + 1e-6f);
            float wv = ratio + SQRTF(ratio * ratio - 1.f);
            float p = EXP2F(-sqkc * LOG2F(wv));
            p = (s <= t) ? p : 0.f;
            lrow[r] += p;
            Pl[(quad * 4 + r) * 36 + ntl * 16 + l16] = (bf16)p;
          }
        }
        ap[ck] = *(const bf16x8*)&Pl[l16 * 36 + quad * 8];
      }
#pragma unroll
      for (int dt = 0; dt < 4; dt++) {
        bf16x8 bv0 = *(const bf16x8*)&Vt[buf][dt * 16 + l16][quad * 8];
        bf16x8 bv1 = *(const bf16x8*)&Vt[buf][dt * 16 + l16][32 + quad * 8];
        o[dt] = __builtin_amdgcn_mfma_f32_16x16x32_bf16(ap[0], bv0, o[dt], 0, 0, 0);
        o[dt] = __builtin_amdgcn_mfma_f32_16x16x32_bf16(ap[1], bv1, o[dt], 0, 0, 0);
      }
    }
  }

  // ---- one deferred l-reduction over the 16 l16 lanes, then write O ----
#pragma unroll
  for (int r = 0; r < 4; r++) {
#pragma unroll
    for (int off = 1; off <= 8; off <<= 1) lrow[r] += __shfl_xor(lrow[r], off);
  }
#pragma unroll
  for (int r = 0; r < 4; r++) {
    const float invl = RCPF(lrow[r]);
    const int t = tb + quad * 4 + r;
#pragma unroll
    for (int dt = 0; dt < 4; dt++) {
      float val = o[dt][r] * invl;
      outp[(size_t)(b * T_ + t) * C_ + h * 64 + dt * 16 + l16] = (bf16)val;
    }
  }
}

// =====================  host-side launch  =====================
extern "C" void kernel_launch(void* const* d_in, const int* in_sizes, int n_in,
                              void* d_out, int out_size, void* d_ws, size_t ws_size,
                              hipStream_t stream) {
  const float* x      = (const float*)d_in[0];
  const float* w_qkv  = (const float*)d_in[1];
  const float* w_out  = (const float*)d_in[2];
  const float* kcb    = (const float*)d_in[3];
  const float* w_uv   = (const float*)d_in[4];
  const float* b_uv   = (const float*)d_in[5];
  const float* w_mlp  = (const float*)d_in[6];
  const float* b_mlp  = (const float*)d_in[7];
  float* out = (float*)d_out;

  const size_t MB = 1024ull * 1024ull;
  char* w = (char*)d_ws;
  bf16*  wqkv_b  = (bf16*)(w + 0);          //  6 MB   [0,6)
  bf16*  wout_b  = (bf16*)(w + 6 * MB);     //  2 MB   [6,8)
  bf16*  wuv_p   = (bf16*)(w + 8 * MB);     // 16 MB   [8,24)  row-permuted {32u,32v}/64
  bf16*  wmlp_b  = (bf16*)(w + 24 * MB);    //  8 MB   [24,32)
  bf16*  hbuf    = (bf16*)(w + 32 * MB);    //  8 MB   [32,40)
  bf16*  qkvbuf  = (bf16*)(w + 40 * MB);    // 24 MB   [40,64) dead after attn
  bf16*  attnbuf = (bf16*)(w + 64 * MB);    //  8 MB   [64,72) dead after wout GEMM
  bf16*  gbuf    = (bf16*)(w + 40 * MB);    // 32 MB   [40,72) over qkv+attn (step 7)
  float* x2buf   = (float*)(w + 72 * MB);   // 16 MB   [72,88) fp32
  float* q0b     = (float*)(w + 88 * MB);                 // 256 KB
  float* k0b     = (float*)(w + 88 * MB + 256 * 1024);    // 256 KB
  float* biasp   = (float*)(w + 88 * MB + 512 * 1024);    //  32 KB (permuted b_uv)
  // total: ~88.6 MB

  // 0) weight casts (+w_uv/b_uv row permutation), single launch
  const int total4 = 786432 + 262144 + 2097152 + 1048576 + 2048;
  cast_all_kernel<<<(total4 + 255) / 256, 256, 0, stream>>>(
      w_qkv, w_out, w_uv, w_mlp, b_uv, wqkv_b, wout_b, wuv_p, wmlp_b, biasp);

  // 1) h = rmsnorm(x)
  rmsnorm_kernel<<<M_, 256, 0, stream>>>(x, hbuf);
  // 2) qkv = h @ w_qkv^T   (256^2, 192 blocks = ONE round, ~37 us)
  gemm256n<<<dim3(M_ / 256, 3072 / 256), 512, 0, stream>>>(hbuf, wqkv_b, qkvbuf, 3072);
  // 3) rotary(q,k) in-place + q0/k0
  rotary_kernel<<<(B_ * T_ * H_) / 4, 256, 0, stream>>>(qkvbuf, kcb, q0b, k0b);
  // 4) hyperbolic flash attention (v9: balanced CU pairs)
  attn_kernel<<<dim3(B_ * H_, 16), 512, 0, stream>>>(qkvbuf, q0b, k0b, kcb, attnbuf);
  // 5) x2 = x + attn @ w_out^T   (128x64 free-run, 512 blocks = 2/CU)
  gemm_fr<1, float, 64><<<dim3(M_ / 128, 1024 / 64), 256, 0, stream>>>(
      attnbuf, wout_b, x2buf, nullptr, x, 1024, 1024);
  // 6) h2 = rmsnorm(x2)
  rmsnorm_kernel<<<M_, 256, 0, stream>>>(x2buf, hbuf);
  // 7) g = swiglu(h2 @ w_uv_p^T + b_uv_p) -> 4096-col bf16  (256^2, R5 structure)
  gemm8_swiglu<<<dim3(M_ / 256, 8192 / 256), 512, 0, stream>>>(hbuf, wuv_p, gbuf, biasp);
  // 8) out = x2 + g @ w_mlp^T + b_mlp   (128x64 free-run, K=4096, 512 blocks = 2/CU)
  gemm_fr<3, float, 64><<<dim3(M_ / 128, 1024 / 64), 256, 0, stream>>>(
      gbuf, wmlp_b, out, b_mlp, x2buf, 1024, 4096);
}

// Round 10
// 370.299 us; speedup vs baseline: 1.0503x; 1.0274x over previous
//
#include <hip/hip_runtime.h>
#include <cstdint>
#include <cmath>

typedef __bf16 bf16;
typedef __attribute__((ext_vector_type(8))) __bf16 bf16x8;
typedef __attribute__((ext_vector_type(4))) __bf16 bf16x4;
typedef __attribute__((ext_vector_type(2))) __bf16 bf16x2;
typedef __attribute__((ext_vector_type(4))) float f32x4;
typedef __attribute__((ext_vector_type(2))) float f32x2;

constexpr int B_ = 2, T_ = 2048, C_ = 1024, H_ = 16, HD_ = 64;
constexpr int M_ = B_ * T_;   // 4096

#define EXP2F(x) __builtin_amdgcn_exp2f(x)
#define LOG2F(x) __builtin_amdgcn_logf(x)
#define SQRTF(x) __builtin_amdgcn_sqrtf(x)
#define RCPF(x)  __builtin_amdgcn_rcpf(x)

// ---- async global->LDS, 16B per lane; LDS dest = wave-uniform base + lane*16 ----
__device__ __forceinline__ void gld16(const void* g, void* l) {
  __builtin_amdgcn_global_load_lds((const __attribute__((address_space(1))) void*)g,
                                   (__attribute__((address_space(3))) void*)l, 16, 0, 0);
}

// ============  PREP: weight casts (+uv perm) + rotary cos/sin table + rmsnorm1  ============
// Segments (gid = blockIdx*256+tid, blocks [0, 16648)):
//   [0, 786432)        w_qkv cast (4 elem/gid)
//   [..,+262144)       w_out cast
//   [..,+2097152)      w_uv cast + {32u,32v}/64 row perm
//   [..,+1048576)      w_mlp cast
//   [4194304,+2048)    b_uv perm (4 elem/gid)
//   [4196352,+65536)   cs table: cstab[t*32+i] = {cos,sin}(t * 10000^(-i/32))
// Blocks [16648, 16648+4096): rmsnorm1 row = blockIdx-16648 (x -> hbuf).
constexpr int CAST_BLOCKS = 16648;   // 4261888 / 256
__global__ __launch_bounds__(256) void prep_kernel(const float* __restrict__ s0,
                                                   const float* __restrict__ s1,
                                                   const float* __restrict__ s2,
                                                   const float* __restrict__ s3,
                                                   const float* __restrict__ s4,
                                                   bf16* __restrict__ d0,
                                                   bf16* __restrict__ d1,
                                                   bf16* __restrict__ d2,
                                                   bf16* __restrict__ d3,
                                                   float* __restrict__ d4,
                                                   float* __restrict__ cstab,
                                                   const float* __restrict__ x,
                                                   bf16* __restrict__ hbuf) {
  __shared__ float wsum[4];
  __shared__ float scale_sh;
  if (blockIdx.x >= CAST_BLOCKS) {      // ---- rmsnorm1 ----
    const int row = blockIdx.x - CAST_BLOCKS;
    const int tid = threadIdx.x;
    const int wave = tid >> 6;
    f32x4 v = *(const f32x4*)(x + (size_t)row * C_ + tid * 4);
    float s = v[0] * v[0] + v[1] * v[1] + v[2] * v[2] + v[3] * v[3];
#pragma unroll
    for (int off = 32; off >= 1; off >>= 1) s += __shfl_xor(s, off);
    if ((tid & 63) == 0) wsum[wave] = s;
    __syncthreads();
    if (tid == 0)
      scale_sh = rsqrtf((wsum[0] + wsum[1] + wsum[2] + wsum[3]) * (1.f / (float)C_) + 1e-6f);
    __syncthreads();
    const float sc = scale_sh;
    bf16x4 o;
    o[0] = (bf16)(v[0] * sc); o[1] = (bf16)(v[1] * sc);
    o[2] = (bf16)(v[2] * sc); o[3] = (bf16)(v[3] * sc);
    *(bf16x4*)(hbuf + (size_t)row * C_ + tid * 4) = o;
    return;
  }
  size_t gid = (size_t)blockIdx.x * 256 + threadIdx.x;
  if (gid >= 786432 + 262144 + 2097152 + 1048576) {
    size_t g4 = gid - (786432 + 262144 + 2097152 + 1048576);
    if (g4 < 2048) {                    // ---- b_uv perm ----
      int r = (int)(g4 * 4);
      int dr;
      if (r < 4096) { int g = r >> 5, i = r & 31; dr = g * 64 + i; }
      else { int j = r - 4096; int g = j >> 5, i = j & 31; dr = g * 64 + 32 + i; }
      *(f32x4*)(d4 + dr) = *(const f32x4*)(s4 + r);
      return;
    }
    size_t tb = g4 - 2048;              // ---- cos/sin table ----
    if (tb >= 65536) return;
    const int t = (int)(tb >> 5), i = (int)(tb & 31);
    const float invf = expf(-((float)i / 32.f) * 9.210340371976184f);
    const float ang = (float)t * invf;
    ((f32x2*)cstab)[tb] = f32x2{cosf(ang), sinf(ang)};
    return;
  }
  const float* src;
  bf16* dst;
  size_t dstoff;
  if (gid < 786432) { src = s0; dst = d0; dstoff = gid * 4; }
  else if (gid < 786432 + 262144) { gid -= 786432; src = s1; dst = d1; dstoff = gid * 4; }
  else if (gid < 786432 + 262144 + 2097152) {
    gid -= 786432 + 262144; src = s2; dst = d2;
    size_t elem = gid * 4;
    int r = (int)(elem >> 10), c = (int)(elem & 1023);
    int dr;
    if (r < 4096) { int g = r >> 5, i = r & 31; dr = g * 64 + i; }
    else { int j = r - 4096; int g = j >> 5, i = j & 31; dr = g * 64 + 32 + i; }
    dstoff = ((size_t)dr << 10) | (size_t)c;
  }
  else { gid -= 786432 + 262144 + 2097152; src = s3; dst = d3; dstoff = gid * 4; }
  f32x4 v = *(const f32x4*)(src + gid * 4);
  bf16x4 o;
  o[0] = (bf16)v[0]; o[1] = (bf16)v[1]; o[2] = (bf16)v[2]; o[3] = (bf16)v[3];
  *(bf16x4*)(dst + dstoff) = o;
}

// =============  128xBN free-running GEMM: C = A @ Bw^T (+bias)(+residual)  =============
// Verified counted-vmcnt 2-barrier/tile schedule (R3-R5), 16x16x32 MFMA.
// MODE 0: C=AB  1: +R  2: +bias  3: +bias+R
template <int MODE, typename OutT, int BN = 128>
__global__ __launch_bounds__(256, 2) void gemm_fr(const bf16* __restrict__ A,
                                                  const bf16* __restrict__ Bw,
                                                  OutT* __restrict__ Cmat,
                                                  const float* __restrict__ bias,
                                                  const float* __restrict__ R,
                                                  int N, int K) {
  constexpr int NTN = BN / 32;            // n-tiles per wave (4 or 2)
  __shared__ __align__(16) bf16 smA[2][128][64];
  __shared__ __align__(16) bf16 smB[2][BN][64];

  const int tid  = threadIdx.x;
  const int wave = tid >> 6, lane = tid & 63;
  const int quad = lane >> 4, l16 = lane & 15;
  const int wm = wave >> 1, wn = wave & 1;
  const int bm = blockIdx.x * 128;
  const int bn = blockIdx.y * BN;

  const int csw = (tid & 7) ^ ((tid >> 3) & 7);
  const bf16* gA = A  + (size_t)(bm + (tid >> 3)) * K + csw * 8;
  const bf16* gB = Bw + (size_t)(bn + (tid >> 3)) * K + csw * 8;
  const int wrow = wave * 8;
  const int r7 = l16 & 7;

  f32x4 acc[4][NTN];
#pragma unroll
  for (int i = 0; i < 4; i++)
#pragma unroll
    for (int j = 0; j < NTN; j++) acc[i][j] = f32x4{0.f, 0.f, 0.f, 0.f};

#define STG_ALL(buf_, tile_) do {                                              \
    _Pragma("unroll")                                                          \
    for (int g = 0; g < 4; g++)                                                \
      gld16(gA + (size_t)(g * 32) * K + (size_t)(tile_) * 64,                  \
            &smA[buf_][g * 32 + wrow][0]);                                     \
    _Pragma("unroll")                                                          \
    for (int g = 0; g < BN / 32; g++)                                          \
      gld16(gB + (size_t)(g * 32) * K + (size_t)(tile_) * 64,                  \
            &smB[buf_][g * 32 + wrow][0]);                                     \
  } while (0)

  const int NT = K >> 6;
  STG_ALL(0, 0);
  STG_ALL(1, 1);
  if (BN == 128) asm volatile("s_waitcnt vmcnt(8)" ::: "memory");
  else           asm volatile("s_waitcnt vmcnt(6)" ::: "memory");
  asm volatile("s_barrier" ::: "memory");

#pragma unroll 1
  for (int t = 0; t < NT; ++t) {
    const int buf = t & 1;
    bf16x8 af[2][4], bfr[2][NTN];
#pragma unroll
    for (int nt = 0; nt < NTN; nt++)
      bfr[0][nt] = *(const bf16x8*)&smB[buf][wn * (BN / 2) + nt * 16 + l16][(quad ^ r7) * 8];
#pragma unroll
    for (int i = 0; i < 4; i++)
      af[0][i] = *(const bf16x8*)&smA[buf][wm * 64 + i * 16 + l16][(quad ^ r7) * 8];
#pragma unroll
    for (int nt = 0; nt < NTN; nt++)
      bfr[1][nt] = *(const bf16x8*)&smB[buf][wn * (BN / 2) + nt * 16 + l16][((4 + quad) ^ r7) * 8];
#pragma unroll
    for (int i = 0; i < 4; i++)
      af[1][i] = *(const bf16x8*)&smA[buf][wm * 64 + i * 16 + l16][((4 + quad) ^ r7) * 8];

    __builtin_amdgcn_s_setprio(1);
#pragma unroll
    for (int i = 0; i < 4; i++)
#pragma unroll
      for (int nt = 0; nt < NTN; nt++)
        acc[i][nt] = __builtin_amdgcn_mfma_f32_16x16x32_bf16(af[0][i], bfr[0][nt], acc[i][nt], 0, 0, 0);
    __builtin_amdgcn_s_setprio(0);
    __builtin_amdgcn_s_setprio(1);
#pragma unroll
    for (int i = 0; i < 4; i++)
#pragma unroll
      for (int nt = 0; nt < NTN; nt++)
        acc[i][nt] = __builtin_amdgcn_mfma_f32_16x16x32_bf16(af[1][i], bfr[1][nt], acc[i][nt], 0, 0, 0);
    __builtin_amdgcn_s_setprio(0);

    if (t + 1 < NT) {
      asm volatile("s_barrier" ::: "memory");
      if (t + 2 < NT) {
        STG_ALL(buf, t + 2);
        if (BN == 128) asm volatile("s_waitcnt vmcnt(8)" ::: "memory");
        else           asm volatile("s_waitcnt vmcnt(6)" ::: "memory");
      } else {
        asm volatile("s_waitcnt vmcnt(0)" ::: "memory");
      }
      asm volatile("s_barrier" ::: "memory");
    }
  }
#undef STG_ALL

#pragma unroll
  for (int mt = 0; mt < 4; mt++) {
    const int row = bm + wm * 64 + mt * 16 + quad * 4;
#pragma unroll
    for (int nt = 0; nt < NTN; nt++) {
      const int col = bn + wn * (BN / 2) + nt * 16 + l16;
      float bval = 0.f;
      if (MODE & 2) bval = bias[col];
#pragma unroll
      for (int r = 0; r < 4; r++) {
        float v = acc[mt][nt][r] + bval;
        if (MODE & 1) v += R[(size_t)(row + r) * N + col];
        Cmat[(size_t)(row + r) * N + col] = (OutT)v;
      }
    }
  }
}

// ==========  256x256 qkv GEMM with FUSED rotary + q0/k0 epilogue  ==========
// Core = verified gemm8 schedule (counted-vmcnt 2-barrier/tile, T2 swizzle, T5).
// Each wave owns ALL 64 cols of one head for its 128 rows; rotary pairing
// (col i <-> i+32) == register pairing acc[mt][ntl] <-> acc[mt][ntl+2].
// cos/sin from precomputed table cstab[t*32+i].  q0/k0 = sqrt(kc + |row|^2)
// via 16-lane shfl reduce (rotation preserves the norm).  v-blocks store plain.
__global__ __launch_bounds__(512, 2) void gemm_qkv_rot(const bf16* __restrict__ A,
                                                       const bf16* __restrict__ Bw,
                                                       bf16* __restrict__ Cmat,
                                                       const float* __restrict__ kcb,
                                                       float* __restrict__ q0b,
                                                       float* __restrict__ k0b,
                                                       const float* __restrict__ cstab) {
  constexpr int K = 1024, NTILE = K / 64, N = 3072;
  __shared__ __align__(16) bf16 smem[2][2][256][64];

  const int tid  = threadIdx.x;
  const int wave = tid >> 6, lane = tid & 63;
  const int quad = lane >> 4, l16 = lane & 15;
  const int wm = wave >> 2, wn = wave & 3;
  const int bm = blockIdx.x * 256;
  const int bn = blockIdx.y * 256;

  const int csw = (tid & 7) ^ ((tid >> 3) & 7);
  const bf16* gA = A  + (size_t)(bm + (tid >> 3)) * K + csw * 8;
  const bf16* gB = Bw + (size_t)(bn + (tid >> 3)) * K + csw * 8;
  const int wrow = wave * 8;
  const int r7 = l16 & 7;

  f32x4 acc[8][4];
#pragma unroll
  for (int i = 0; i < 8; i++)
#pragma unroll
    for (int j = 0; j < 4; j++) acc[i][j] = f32x4{0.f, 0.f, 0.f, 0.f};

#define STAGE8(buf_, tile_, h_) do {                                          \
    const int mat_ = (h_) >> 1;                                               \
    const int r0_  = ((h_) & 1) * 128;                                        \
    const bf16* s_ = (mat_ ? gB : gA) + (size_t)r0_ * K + (size_t)(tile_) * 64; \
    bf16* d_ = &smem[buf_][mat_][r0_ + wrow][0];                              \
    gld16(s_, d_);                                                            \
    gld16(s_ + (size_t)64 * K, d_ + 64 * 64);                                 \
  } while (0)
#define STAGE_ALL(buf_, tile_) do {                                           \
    STAGE8(buf_, tile_, 0); STAGE8(buf_, tile_, 1);                           \
    STAGE8(buf_, tile_, 2); STAGE8(buf_, tile_, 3); } while (0)

  STAGE_ALL(0, 0);
  STAGE_ALL(1, 1);
  asm volatile("s_waitcnt vmcnt(8)" ::: "memory");
  asm volatile("s_barrier" ::: "memory");

#pragma unroll 1
  for (int t = 0; t < NTILE; ++t) {
    const int buf = t & 1;
    bf16x8 afX[2][4], bfX[2][4];
#pragma unroll
    for (int nt = 0; nt < 4; nt++)
      bfX[0][nt] = *(const bf16x8*)&smem[buf][1][wn * 64 + nt * 16 + l16][(quad ^ r7) * 8];
#pragma unroll
    for (int i = 0; i < 4; i++)
      afX[0][i] = *(const bf16x8*)&smem[buf][0][wm * 128 + i * 16 + l16][(quad ^ r7) * 8];

#pragma unroll
    for (int ph = 0; ph < 4; ph++) {
      const int mh = ph & 1;
      const int ks = ph >> 1;
      if (ph == 0) {
#pragma unroll
        for (int i = 0; i < 4; i++)
          afX[1][i] = *(const bf16x8*)&smem[buf][0][wm * 128 + (4 + i) * 16 + l16][(quad ^ r7) * 8];
      } else if (ph == 1) {
#pragma unroll
        for (int nt = 0; nt < 4; nt++)
          bfX[1][nt] = *(const bf16x8*)&smem[buf][1][wn * 64 + nt * 16 + l16][((4 + quad) ^ r7) * 8];
#pragma unroll
        for (int i = 0; i < 4; i++)
          afX[0][i] = *(const bf16x8*)&smem[buf][0][wm * 128 + i * 16 + l16][((4 + quad) ^ r7) * 8];
      } else if (ph == 2) {
#pragma unroll
        for (int i = 0; i < 4; i++)
          afX[1][i] = *(const bf16x8*)&smem[buf][0][wm * 128 + (4 + i) * 16 + l16][((4 + quad) ^ r7) * 8];
      }
      __builtin_amdgcn_s_setprio(1);
#pragma unroll
      for (int i = 0; i < 4; i++)
#pragma unroll
        for (int nt = 0; nt < 4; nt++)
          acc[mh * 4 + i][nt] =
              __builtin_amdgcn_mfma_f32_16x16x32_bf16(afX[mh][i], bfX[ks][nt], acc[mh * 4 + i][nt], 0, 0, 0);
      __builtin_amdgcn_s_setprio(0);
    }

    if (t + 1 < NTILE) {
      asm volatile("s_barrier" ::: "memory");
      if (t + 2 < NTILE) {
        STAGE_ALL(buf, t + 2);
        asm volatile("s_waitcnt vmcnt(8)" ::: "memory");
      } else {
        asm volatile("s_waitcnt vmcnt(0)" ::: "memory");
      }
      asm volatile("s_barrier" ::: "memory");
    }
  }
#undef STAGE_ALL
#undef STAGE8

  if (bn < 2048) {
    // ---- fused rotary + q0/k0 epilogue (q: bn<1024, k: 1024<=bn<2048) ----
    const int h = ((bn & 1023) >> 6) + wn;      // head 0..15
    const float kc = kcb[h];
    float* dst = ((bn < 1024) ? q0b : k0b) + (size_t)h * T_;
#pragma unroll
    for (int mt = 0; mt < 8; mt++) {
#pragma unroll
      for (int r = 0; r < 4; r++) {
        const int row = bm + wm * 128 + mt * 16 + quad * 4 + r;
        const int tt = row & 2047, bb = row >> 11;
        float o_[4];
        float nrm = 0.f;
#pragma unroll
        for (int ntl = 0; ntl < 2; ntl++) {
          const int i = ntl * 16 + l16;
          f32x2 cs = ((const f32x2*)cstab)[tt * 32 + i];
          float x1 = acc[mt][ntl][r], x2 = acc[mt][ntl + 2][r];
          float o1 = x1 * cs[0] + x2 * cs[1];
          float o2 = x2 * cs[0] - x1 * cs[1];
          o_[ntl] = o1; o_[ntl + 2] = o2;
          nrm += o1 * o1 + o2 * o2;
        }
#pragma unroll
        for (int off = 1; off <= 8; off <<= 1) nrm += __shfl_xor(nrm, off);
        if (l16 == 0) dst[(size_t)bb * (H_ * T_) + tt] = SQRTF(kc + nrm);
#pragma unroll
        for (int nt = 0; nt < 4; nt++)
          Cmat[(size_t)row * N + bn + wn * 64 + nt * 16 + l16] = (bf16)o_[nt];
      }
    }
  } else {
    // ---- plain store (v region) ----
#pragma unroll
    for (int mt = 0; mt < 8; mt++) {
      const int row = bm + wm * 128 + mt * 16 + quad * 4;
#pragma unroll
      for (int nt = 0; nt < 4; nt++) {
        const int col = bn + wn * 64 + nt * 16 + l16;
#pragma unroll
        for (int r = 0; r < 4; r++)
          Cmat[(size_t)(row + r) * N + col] = (bf16)acc[mt][nt][r];
      }
    }
  }
}

// =====================  256x256 GEMM + swiglu epilogue (R5 structure)  =====================
__global__ __launch_bounds__(512, 2) void gemm8_swiglu(const bf16* __restrict__ A,
                                                       const bf16* __restrict__ Bw,
                                                       bf16* __restrict__ Cmat,
                                                       const float* __restrict__ bias) {
  constexpr int K = 1024, NTILE = K / 64;
  __shared__ __align__(16) bf16 smem[2][2][256][64];

  const int tid  = threadIdx.x;
  const int wave = tid >> 6, lane = tid & 63;
  const int quad = lane >> 4, l16 = lane & 15;
  const int wm = wave >> 2, wn = wave & 3;
  const int bm = blockIdx.x * 256;
  const int bn = blockIdx.y * 256;

  const int csw = (tid & 7) ^ ((tid >> 3) & 7);
  const bf16* gA = A  + (size_t)(bm + (tid >> 3)) * K + csw * 8;
  const bf16* gB = Bw + (size_t)(bn + (tid >> 3)) * K + csw * 8;
  const int wrow = wave * 8;
  const int r7 = l16 & 7;

  f32x4 acc[8][4];
#pragma unroll
  for (int i = 0; i < 8; i++)
#pragma unroll
    for (int j = 0; j < 4; j++) acc[i][j] = f32x4{0.f, 0.f, 0.f, 0.f};

#define STAGE8(buf_, tile_, h_) do {                                          \
    const int mat_ = (h_) >> 1;                                               \
    const int r0_  = ((h_) & 1) * 128;                                        \
    const bf16* s_ = (mat_ ? gB : gA) + (size_t)r0_ * K + (size_t)(tile_) * 64; \
    bf16* d_ = &smem[buf_][mat_][r0_ + wrow][0];                              \
    gld16(s_, d_);                                                            \
    gld16(s_ + (size_t)64 * K, d_ + 64 * 64);                                 \
  } while (0)
#define STAGE_ALL(buf_, tile_) do {                                           \
    STAGE8(buf_, tile_, 0); STAGE8(buf_, tile_, 1);                           \
    STAGE8(buf_, tile_, 2); STAGE8(buf_, tile_, 3); } while (0)

  STAGE_ALL(0, 0);
  STAGE_ALL(1, 1);
  asm volatile("s_waitcnt vmcnt(8)" ::: "memory");
  asm volatile("s_barrier" ::: "memory");

#pragma unroll 1
  for (int t = 0; t < NTILE; ++t) {
    const int buf = t & 1;
    bf16x8 afX[2][4], bfX[2][4];
#pragma unroll
    for (int nt = 0; nt < 4; nt++)
      bfX[0][nt] = *(const bf16x8*)&smem[buf][1][wn * 64 + nt * 16 + l16][(quad ^ r7) * 8];
#pragma unroll
    for (int i = 0; i < 4; i++)
      afX[0][i] = *(const bf16x8*)&smem[buf][0][wm * 128 + i * 16 + l16][(quad ^ r7) * 8];

#pragma unroll
    for (int ph = 0; ph < 4; ph++) {
      const int mh = ph & 1;
      const int ks = ph >> 1;
      if (ph == 0) {
#pragma unroll
        for (int i = 0; i < 4; i++)
          afX[1][i] = *(const bf16x8*)&smem[buf][0][wm * 128 + (4 + i) * 16 + l16][(quad ^ r7) * 8];
      } else if (ph == 1) {
#pragma unroll
        for (int nt = 0; nt < 4; nt++)
          bfX[1][nt] = *(const bf16x8*)&smem[buf][1][wn * 64 + nt * 16 + l16][((4 + quad) ^ r7) * 8];
#pragma unroll
        for (int i = 0; i < 4; i++)
          afX[0][i] = *(const bf16x8*)&smem[buf][0][wm * 128 + i * 16 + l16][((4 + quad) ^ r7) * 8];
      } else if (ph == 2) {
#pragma unroll
        for (int i = 0; i < 4; i++)
          afX[1][i] = *(const bf16x8*)&smem[buf][0][wm * 128 + (4 + i) * 16 + l16][((4 + quad) ^ r7) * 8];
      }
      __builtin_amdgcn_s_setprio(1);
#pragma unroll
      for (int i = 0; i < 4; i++)
#pragma unroll
        for (int nt = 0; nt < 4; nt++)
          acc[mh * 4 + i][nt] =
              __builtin_amdgcn_mfma_f32_16x16x32_bf16(afX[mh][i], bfX[ks][nt], acc[mh * 4 + i][nt], 0, 0, 0);
      __builtin_amdgcn_s_setprio(0);
    }

    if (t + 1 < NTILE) {
      asm volatile("s_barrier" ::: "memory");
      if (t + 2 < NTILE) {
        STAGE_ALL(buf, t + 2);
        asm volatile("s_waitcnt vmcnt(8)" ::: "memory");
      } else {
        asm volatile("s_waitcnt vmcnt(0)" ::: "memory");
      }
      asm volatile("s_barrier" ::: "memory");
    }
  }
#undef STAGE_ALL
#undef STAGE8

  const int cg = (bn >> 1) + wn * 32;
#pragma unroll
  for (int ntl = 0; ntl < 2; ntl++) {
    const float bu = bias[bn + wn * 64 + ntl * 16 + l16];
    const float bv = bias[bn + wn * 64 + 32 + ntl * 16 + l16];
    const int col = cg + ntl * 16 + l16;
#pragma unroll
    for (int mt = 0; mt < 8; mt++) {
      const int row = bm + wm * 128 + mt * 16 + quad * 4;
#pragma unroll
      for (int r = 0; r < 4; r++) {
        float u = acc[mt][ntl][r] + bu;
        float v = acc[mt][ntl + 2][r] + bv;
        float sig = RCPF(1.f + EXP2F(-v * 1.44269504f));
        Cmat[(size_t)(row + r) * 4096 + col] = (bf16)(u * v * sig);
      }
    }
  }
}

// =====================  RMSNorm: fp32 in -> bf16 out (row = 1024)  =====================
__global__ __launch_bounds__(256) void rmsnorm_kernel(const float* __restrict__ X,
                                                      bf16* __restrict__ O) {
  const int row = blockIdx.x;
  const int tid = threadIdx.x;
  const int wave = tid >> 6;
  f32x4 v = *(const f32x4*)(X + (size_t)row * C_ + tid * 4);
  float s = v[0] * v[0] + v[1] * v[1] + v[2] * v[2] + v[3] * v[3];
#pragma unroll
  for (int off = 32; off >= 1; off >>= 1) s += __shfl_xor(s, off);
  __shared__ float wsum[4];
  __shared__ float scale_sh;
  if ((tid & 63) == 0) wsum[wave] = s;
  __syncthreads();
  if (tid == 0)
    scale_sh = rsqrtf((wsum[0] + wsum[1] + wsum[2] + wsum[3]) * (1.f / (float)C_) + 1e-6f);
  __syncthreads();
  const float sc = scale_sh;
  bf16x4 o;
  o[0] = (bf16)(v[0] * sc); o[1] = (bf16)(v[1] * sc);
  o[2] = (bf16)(v[2] * sc); o[3] = (bf16)(v[3] * sc);
  *(bf16x4*)(O + (size_t)row * C_ + tid * 4) = o;
}

// =====================  Hyperbolic flash attention (v9)  =====================
// v9: CU-pair-complementary ty remap (pairs sum to 34 iters/CU).
__global__ __launch_bounds__(512) void attn_kernel(const bf16* __restrict__ qkv,
                                                   const float* __restrict__ q0b,
                                                   const float* __restrict__ k0b,
                                                   const float* __restrict__ kcb,
                                                   bf16* __restrict__ outp) {
  __shared__ __align__(16) bf16 Kls[2][64][72];
  __shared__ __align__(16) bf16 Vt[2][64][68];
  __shared__ __align__(16) bf16 Pls[8][16 * 36];
  __shared__ float k0s[2][64];

  const int tid = threadIdx.x;
  const int wave = tid >> 6, lane = tid & 63;
  const int quad = lane >> 4, l16 = lane & 15;
  const int bh = blockIdx.x;
  const int b = bh >> 4, h = bh & 15;

  const float kc = kcb[h];
  const float inv_kc = 1.f / kc;
  const float sqkc = SQRTF(kc);
  const int role = tid >> 8;
  const int st = tid & 255;
  const int sp = st & 31, dq = st >> 5;
  bf16* Pl = Pls[wave];
  const float* q0base = q0b + (size_t)(b * H_ + h) * T_;
  const float* k0base = k0b + (size_t)(b * H_ + h) * T_;

  const int yb = (int)blockIdx.y;
  const int ty = (yb < 8) ? (15 - yb) : (yb - 8);
  const int t0 = ty * 128;
  const int tb = t0 + wave * 16;
  const int nIter = 2 * ty + 2;

  const bf16* qrow = qkv + (size_t)(b * T_ + tb + l16) * 3072 + h * 64;
  bf16x8 aq0 = *(const bf16x8*)(qrow + quad * 8);
  bf16x8 aq1 = *(const bf16x8*)(qrow + 32 + quad * 8);
  float q0r[4];
#pragma unroll
  for (int r = 0; r < 4; r++) q0r[r] = q0base[tb + quad * 4 + r];

  f32x4 o[4];
#pragma unroll
  for (int dt = 0; dt < 4; dt++) o[dt] = f32x4{0.f, 0.f, 0.f, 0.f};
  float lrow[4] = {0.f, 0.f, 0.f, 0.f};

  const bf16* base = qkv + (size_t)b * T_ * 3072 + 1024 + role * 1024 + h * 64 + dq * 8;
  bf16x8 pf_a = *(const bf16x8*)(base + (size_t)(2 * sp) * 3072);
  bf16x8 pf_b = *(const bf16x8*)(base + (size_t)(2 * sp + 1) * 3072);
  float k0v = (tid < 64) ? k0base[tid] : 0.f;

  for (int it = 0; it < nIter; ++it) {
    const int s0 = it * 64;
    const int buf = it & 1;
    if (role == 0) {
      *(bf16x8*)&Kls[buf][2 * sp][dq * 8]     = pf_a;
      *(bf16x8*)&Kls[buf][2 * sp + 1][dq * 8] = pf_b;
    } else {
#pragma unroll
      for (int i2 = 0; i2 < 8; i2++) {
        bf16x2 pr;
        pr[0] = pf_a[i2];
        pr[1] = pf_b[i2];
        *(bf16x2*)&Vt[buf][dq * 8 + i2][2 * sp] = pr;
      }
    }
    if (tid < 64) k0s[buf][tid] = k0v;
    __syncthreads();

    const int s0n = (it + 1 < nIter) ? s0 + 64 : s0;
    pf_a = *(const bf16x8*)(base + (size_t)(s0n + 2 * sp) * 3072);
    pf_b = *(const bf16x8*)(base + (size_t)(s0n + 2 * sp + 1) * 3072);
    if (tid < 64) k0v = k0base[s0n + tid];

    if (s0 <= tb + 15) {
      f32x4 sc[4];
#pragma unroll
      for (int nt = 0; nt < 4; nt++) {
        sc[nt] = f32x4{0.f, 0.f, 0.f, 0.f};
        bf16x8 b0 = *(const bf16x8*)&Kls[buf][nt * 16 + l16][quad * 8];
        bf16x8 b1 = *(const bf16x8*)&Kls[buf][nt * 16 + l16][32 + quad * 8];
        sc[nt] = __builtin_amdgcn_mfma_f32_16x16x32_bf16(aq0, b0, sc[nt], 0, 0, 0);
        sc[nt] = __builtin_amdgcn_mfma_f32_16x16x32_bf16(aq1, b1, sc[nt], 0, 0, 0);
      }

      bf16x8 ap[2];
#pragma unroll
      for (int ck = 0; ck < 2; ck++) {
#pragma unroll
        for (int ntl = 0; ntl < 2; ntl++) {
          const int nt = ck * 2 + ntl;
          const float k0c = k0s[buf][nt * 16 + l16];
          const int s = s0 + nt * 16 + l16;
#pragma unroll
          for (int r = 0; r < 4; r++) {
            const int t = tb + quad * 4 + r;
            float lor = sc[nt][r] - q0r[r] * k0c;
            float ratio = fmaxf(-lor * inv_kc, 1.f + 1e-6f);
            float wv = ratio + SQRTF(ratio * ratio - 1.f);
            float p = EXP2F(-sqkc * LOG2F(wv));
            p = (s <= t) ? p : 0.f;
            lrow[r] += p;
            Pl[(quad * 4 + r) * 36 + ntl * 16 + l16] = (bf16)p;
          }
        }
        ap[ck] = *(const bf16x8*)&Pl[l16 * 36 + quad * 8];
      }
#pragma unroll
      for (int dt = 0; dt < 4; dt++) {
        bf16x8 bv0 = *(const bf16x8*)&Vt[buf][dt * 16 + l16][quad * 8];
        bf16x8 bv1 = *(const bf16x8*)&Vt[buf][dt * 16 + l16][32 + quad * 8];
        o[dt] = __builtin_amdgcn_mfma_f32_16x16x32_bf16(ap[0], bv0, o[dt], 0, 0, 0);
        o[dt] = __builtin_amdgcn_mfma_f32_16x16x32_bf16(ap[1], bv1, o[dt], 0, 0, 0);
      }
    }
  }

#pragma unroll
  for (int r = 0; r < 4; r++) {
#pragma unroll
    for (int off = 1; off <= 8; off <<= 1) lrow[r] += __shfl_xor(lrow[r], off);
  }
#pragma unroll
  for (int r = 0; r < 4; r++) {
    const float invl = RCPF(lrow[r]);
    const int t = tb + quad * 4 + r;
#pragma unroll
    for (int dt = 0; dt < 4; dt++) {
      float val = o[dt][r] * invl;
      outp[(size_t)(b * T_ + t) * C_ + h * 64 + dt * 16 + l16] = (bf16)val;
    }
  }
}

// =====================  host-side launch  =====================
extern "C" void kernel_launch(void* const* d_in, const int* in_sizes, int n_in,
                              void* d_out, int out_size, void* d_ws, size_t ws_size,
                              hipStream_t stream) {
  const float* x      = (const float*)d_in[0];
  const float* w_qkv  = (const float*)d_in[1];
  const float* w_out  = (const float*)d_in[2];
  const float* kcb    = (const float*)d_in[3];
  const float* w_uv   = (const float*)d_in[4];
  const float* b_uv   = (const float*)d_in[5];
  const float* w_mlp  = (const float*)d_in[6];
  const float* b_mlp  = (const float*)d_in[7];
  float* out = (float*)d_out;

  const size_t MB = 1024ull * 1024ull;
  char* w = (char*)d_ws;
  bf16*  wqkv_b  = (bf16*)(w + 0);          //  6 MB   [0,6)
  bf16*  wout_b  = (bf16*)(w + 6 * MB);     //  2 MB   [6,8)
  bf16*  wuv_p   = (bf16*)(w + 8 * MB);     // 16 MB   [8,24)  row-permuted {32u,32v}/64
  bf16*  wmlp_b  = (bf16*)(w + 24 * MB);    //  8 MB   [24,32)
  bf16*  hbuf    = (bf16*)(w + 32 * MB);    //  8 MB   [32,40)
  bf16*  qkvbuf  = (bf16*)(w + 40 * MB);    // 24 MB   [40,64) dead after attn
  bf16*  attnbuf = (bf16*)(w + 64 * MB);    //  8 MB   [64,72) dead after wout GEMM
  float* cstab   = (float*)(w + 64 * MB);   // 512 KB  OVERLAPS attnbuf: table read at
                                            // step 2, attnbuf first written at step 4
  bf16*  gbuf    = (bf16*)(w + 40 * MB);    // 32 MB   [40,72) over qkv+attn (step 7)
  float* x2buf   = (float*)(w + 72 * MB);   // 16 MB   [72,88) fp32
  float* q0b     = (float*)(w + 88 * MB);                 // 256 KB
  float* k0b     = (float*)(w + 88 * MB + 256 * 1024);    // 256 KB
  float* biasp   = (float*)(w + 88 * MB + 512 * 1024);    //  32 KB (permuted b_uv)
  // total: ~88.6 MB

  // 0) prep: weight casts + uv perm + cos/sin table + rmsnorm1  (one launch)
  prep_kernel<<<CAST_BLOCKS + M_, 256, 0, stream>>>(
      w_qkv, w_out, w_uv, w_mlp, b_uv, wqkv_b, wout_b, wuv_p, wmlp_b, biasp,
      cstab, x, hbuf);
  // 2) qkv = h @ w_qkv^T with FUSED rotary + q0/k0  (256^2, 192 blocks = one round)
  gemm_qkv_rot<<<dim3(M_ / 256, 3072 / 256), 512, 0, stream>>>(
      hbuf, wqkv_b, qkvbuf, kcb, q0b, k0b, cstab);
  // 4) hyperbolic flash attention (v9: balanced CU pairs)
  attn_kernel<<<dim3(B_ * H_, 16), 512, 0, stream>>>(qkvbuf, q0b, k0b, kcb, attnbuf);
  // 5) x2 = x + attn @ w_out^T   (128x64 free-run, 512 blocks = 2/CU)
  gemm_fr<1, float, 64><<<dim3(M_ / 128, 1024 / 64), 256, 0, stream>>>(
      attnbuf, wout_b, x2buf, nullptr, x, 1024, 1024);
  // 6) h2 = rmsnorm(x2)
  rmsnorm_kernel<<<M_, 256, 0, stream>>>(x2buf, hbuf);
  // 7) g = swiglu(h2 @ w_uv_p^T + b_uv_p) -> 4096-col bf16  (256^2)
  gemm8_swiglu<<<dim3(M_ / 256, 8192 / 256), 512, 0, stream>>>(hbuf, wuv_p, gbuf, biasp);
  // 8) out = x2 + g @ w_mlp^T + b_mlp   (128x64 free-run, K=4096, 512 blocks = 2/CU)
  gemm_fr<3, float, 64><<<dim3(M_ / 128, 1024 / 64), 256, 0, stream>>>(
      gbuf, wmlp_b, out, b_mlp, x2buf, 1024, 4096);
}